// Round 1
// baseline (4741.489 us; speedup 1.0000x reference)
//
#include <hip/hip_runtime.h>

// Problem constants (AttentionalCopula)
constexpr int kB = 16, kD = 256, kNH = 512, kNV = 256, kW = 768;
constexpr int kL = 4, kH = 8, kA = 64, kHA = 512, kM = 512, kR = 128;

// ---------------- build ki = [hist||u ; pred||u] : [B, W, 257] ----------------
__global__ void build_ki_kernel(const float* __restrict__ hist,
                                const float* __restrict__ hist_u,
                                const float* __restrict__ pred,
                                const float* __restrict__ pred_u,
                                float* __restrict__ ki) {
  int i = blockIdx.x * 256 + threadIdx.x;
  const int total = kB * kW * 257;
  if (i >= total) return;
  int d = i % 257;
  int bw = i / 257;
  int w = bw % kW;
  int b = bw / kW;
  float v;
  if (w < kNH) {
    v = (d < kD) ? hist[((size_t)b * kNH + w) * kD + d] : hist_u[b * kNH + w];
  } else {
    int p = w - kNH;
    v = (d < kD) ? pred[((size_t)b * kNV + p) * kD + d] : pred_u[b * kNV + p];
  }
  ki[i] = v;
}

// ------------- repack key/val weights for layer l: [H,257,A] -> [257, H*A] -------------
__global__ void repack_w_kernel(const float* __restrict__ kw,
                                const float* __restrict__ vw,
                                float* __restrict__ kwp,
                                float* __restrict__ vwp, int l) {
  int i = blockIdx.x * 256 + threadIdx.x;
  const int total = 257 * kHA;
  if (i >= total) return;
  int col = i % kHA;  // h*64 + a
  int d = i / kHA;
  int h = col / kA;
  int a = col % kA;
  size_t src = (((size_t)l * kH + h) * 257 + d) * kA + a;
  kwp[i] = kw[src];
  vwp[i] = vw[src];
}

// ---------------- fp32 GEMM: C[M,N] = A[M,K] @ B[K,N] + bias (opt relu) ----------------
// 64x64 tile per 256-thread block, 4x4 per thread, K-chunks of 16 (K=257 handled).
template <bool RELU>
__global__ __launch_bounds__(256) void gemm_bias_kernel(
    const float* __restrict__ A, const float* __restrict__ Bm,
    const float* __restrict__ bias, float* __restrict__ C,
    int M, int N, int K) {
  __shared__ float As[16][68];  // [k][m], padded: row = 272B (16B aligned)
  __shared__ float Bs[16][68];  // [k][n], padded
  const int tx = threadIdx.x & 15;
  const int ty = threadIdx.x >> 4;
  const int bm = blockIdx.y * 64;
  const int bn = blockIdx.x * 64;
  float acc[4][4] = {};
  for (int k0 = 0; k0 < K; k0 += 16) {
    for (int i = threadIdx.x; i < 1024; i += 256) {
      int m = i >> 4, k = i & 15;
      float v = 0.f;
      if (k0 + k < K) v = A[(size_t)(bm + m) * K + k0 + k];
      As[k][m] = v;
    }
    for (int i = threadIdx.x; i < 1024; i += 256) {
      int k = i >> 6, n = i & 63;
      float v = 0.f;
      if (k0 + k < K) v = Bm[(size_t)(k0 + k) * N + bn + n];
      Bs[k][n] = v;
    }
    __syncthreads();
#pragma unroll
    for (int kk = 0; kk < 16; ++kk) {
      float4 av = *(const float4*)&As[kk][ty * 4];
      float4 bv = *(const float4*)&Bs[kk][tx * 4];
      float a_[4] = {av.x, av.y, av.z, av.w};
      float b_[4] = {bv.x, bv.y, bv.z, bv.w};
#pragma unroll
      for (int i = 0; i < 4; ++i)
#pragma unroll
        for (int j = 0; j < 4; ++j) acc[i][j] += a_[i] * b_[j];
    }
    __syncthreads();
  }
#pragma unroll
  for (int i = 0; i < 4; ++i) {
    int m = bm + ty * 4 + i;
    int n0 = bn + tx * 4;
    float4 o;
    o.x = acc[i][0] + bias[n0 + 0];
    o.y = acc[i][1] + bias[n0 + 1];
    o.z = acc[i][2] + bias[n0 + 2];
    o.w = acc[i][3] + bias[n0 + 3];
    if (RELU) {
      o.x = fmaxf(o.x, 0.f); o.y = fmaxf(o.y, 0.f);
      o.z = fmaxf(o.z, 0.f); o.w = fmaxf(o.w, 0.f);
    }
    *(float4*)&C[(size_t)m * N + n0] = o;
  }
}

// ---------------- flash attention: one thread per query, per (b,h) ----------------
// att:[B*NV, HA] (q = att[b,v, h*64 .. ]), keys/vals:[B*W, HA] col=(h*64+a)
// mask: valid w < NH + v ; scale = 1/8 ; out:[B*NV, HA]
__global__ __launch_bounds__(128) void attn_kernel(
    const float* __restrict__ att, const float* __restrict__ keys,
    const float* __restrict__ vals, float* __restrict__ out) {
  const int b = blockIdx.z, h = blockIdx.y;
  const int v = blockIdx.x * 128 + (int)threadIdx.x;
  __shared__ float Ks[64][64];
  __shared__ float Vs[64][64];
  float q[64], o[64];
  const float* qptr = att + ((size_t)(b * kNV + v) * kHA + h * kA);
#pragma unroll
  for (int i = 0; i < 64; ++i) { q[i] = qptr[i]; o[i] = 0.f; }
  float mmax = -1e30f, lsum = 0.f;
  const int wlimit = kNH + v;                                // valid: w < wlimit
  const int wmax_blk = kNH + blockIdx.x * 128 + 127;         // max wlimit in block
  for (int c0 = 0; c0 < kW; c0 += 64) {
    if (c0 > wmax_blk) break;  // uniform across block
    const float* kbase = keys + ((size_t)(b * kW + c0) * kHA + h * kA);
    const float* vbase = vals + ((size_t)(b * kW + c0) * kHA + h * kA);
    for (int i = threadIdx.x; i < 1024; i += 128) {
      int r = i >> 4, c4 = i & 15;
      *(float4*)&Ks[r][c4 * 4] = *(const float4*)(kbase + (size_t)r * kHA + c4 * 4);
      *(float4*)&Vs[r][c4 * 4] = *(const float4*)(vbase + (size_t)r * kHA + c4 * 4);
    }
    __syncthreads();
    int plim = min(64, wlimit - c0);
    for (int p = 0; p < plim; ++p) {
      float s = 0.f;
#pragma unroll
      for (int i4 = 0; i4 < 16; ++i4) {
        float4 kv = *(const float4*)&Ks[p][i4 * 4];
        s += q[i4 * 4 + 0] * kv.x + q[i4 * 4 + 1] * kv.y +
             q[i4 * 4 + 2] * kv.z + q[i4 * 4 + 3] * kv.w;
      }
      s *= 0.125f;
      float mnew = fmaxf(mmax, s);
      float corr = __expf(mmax - mnew);
      float pexp = __expf(s - mnew);
      lsum = lsum * corr + pexp;
#pragma unroll
      for (int i4 = 0; i4 < 16; ++i4) {
        float4 vv = *(const float4*)&Vs[p][i4 * 4];
        o[i4 * 4 + 0] = o[i4 * 4 + 0] * corr + pexp * vv.x;
        o[i4 * 4 + 1] = o[i4 * 4 + 1] * corr + pexp * vv.y;
        o[i4 * 4 + 2] = o[i4 * 4 + 2] * corr + pexp * vv.z;
        o[i4 * 4 + 3] = o[i4 * 4 + 3] * corr + pexp * vv.w;
      }
      mmax = mnew;
    }
    __syncthreads();
  }
  float inv = 1.f / lsum;
  float* optr = out + ((size_t)(b * kNV + v) * kHA + h * kA);
#pragma unroll
  for (int i = 0; i < 64; ++i) optr[i] = o[i] * inv;
}

// ---------------- att = LN(att + add) * g + b, row width HA=512 ----------------
__global__ __launch_bounds__(256) void add_ln_kernel(
    float* __restrict__ att, const float* __restrict__ add,
    const float* __restrict__ g, const float* __restrict__ be) {
  const int row = blockIdx.x;
  const int t = threadIdx.x;
  float* ar = att + (size_t)row * kHA;
  const float* dr = add + (size_t)row * kHA;
  float x0 = ar[t] + dr[t];
  float x1 = ar[t + 256] + dr[t + 256];
  float s = x0 + x1, sq = x0 * x0 + x1 * x1;
  for (int off = 32; off; off >>= 1) {
    s += __shfl_down(s, off);
    sq += __shfl_down(sq, off);
  }
  __shared__ float ssum[4], ssq[4], stats[2];
  if ((t & 63) == 0) { ssum[t >> 6] = s; ssq[t >> 6] = sq; }
  __syncthreads();
  if (t == 0) {
    float S = ssum[0] + ssum[1] + ssum[2] + ssum[3];
    float Q = ssq[0] + ssq[1] + ssq[2] + ssq[3];
    float mean = S * (1.f / kHA);
    float var = Q * (1.f / kHA) - mean * mean;
    stats[0] = mean;
    stats[1] = rsqrtf(var + 1e-5f);
  }
  __syncthreads();
  float mean = stats[0], inv = stats[1];
  ar[t] = g[t] * (x0 - mean) * inv + be[t];
  ar[t + 256] = g[t + 256] * (x1 - mean) * inv + be[t + 256];
}

// ---------------- loss: out[b] = -sum_{v>=1} (log R + logit[tgt] - lse) ----------------
__global__ __launch_bounds__(256) void loss_kernel(
    const float* __restrict__ logits, const float* __restrict__ pred_u,
    float* __restrict__ out) {
  const int b = blockIdx.x;
  const int t = threadIdx.x;  // v = t, skip v==0
  float lp = 0.f;
  if (t >= 1) {
    const float* row = logits + (size_t)(b * kNV + t) * kR;
    float mx = -1e30f;
    for (int i = 0; i < kR; ++i) mx = fmaxf(mx, row[i]);
    float se = 0.f;
    for (int i = 0; i < kR; ++i) se += expf(row[i] - mx);
    float lse = mx + logf(se);
    float u = pred_u[b * kNV + t];
    int tgt = (int)floorf(u * (float)kR);
    tgt = max(0, min(kR - 1, tgt));
    lp = logf((float)kR) + row[tgt] - lse;
  }
  for (int off = 32; off; off >>= 1) lp += __shfl_down(lp, off);
  __shared__ float red[4];
  if ((t & 63) == 0) red[t >> 6] = lp;
  __syncthreads();
  if (t == 0) out[b] = -(red[0] + red[1] + red[2] + red[3]);
}

extern "C" void kernel_launch(void* const* d_in, const int* in_sizes, int n_in,
                              void* d_out, int out_size, void* d_ws, size_t ws_size,
                              hipStream_t stream) {
  const float* hist   = (const float*)d_in[0];
  const float* hist_u = (const float*)d_in[1];
  const float* pred   = (const float*)d_in[2];
  const float* pred_u = (const float*)d_in[3];
  const float* ds_w   = (const float*)d_in[4];
  const float* ds_b   = (const float*)d_in[5];
  const float* key_w  = (const float*)d_in[6];
  const float* key_b  = (const float*)d_in[7];
  const float* val_w  = (const float*)d_in[8];
  const float* val_b  = (const float*)d_in[9];
  const float* ln1_g  = (const float*)d_in[10];
  const float* ln1_b  = (const float*)d_in[11];
  const float* ln2_g  = (const float*)d_in[12];
  const float* ln2_b  = (const float*)d_in[13];
  const float* ff_w1  = (const float*)d_in[14];
  const float* ff_b1  = (const float*)d_in[15];
  const float* ff_w2  = (const float*)d_in[16];
  const float* ff_b2  = (const float*)d_in[17];
  const float* ff_w3  = (const float*)d_in[18];
  const float* ff_b3  = (const float*)d_in[19];
  const float* de_w   = (const float*)d_in[20];
  const float* de_b   = (const float*)d_in[21];
  float* out = (float*)d_out;

  // workspace layout (floats); total ~24.9M floats ~ 100 MB
  float* ws = (float*)d_ws;
  size_t off = 0;
  float* ki   = ws + off; off += (size_t)kB * kW * 257;   // 3,157,248
  float* kwp  = ws + off; off += (size_t)257 * kHA;       // 131,584
  float* vwp  = ws + off; off += (size_t)257 * kHA;
  float* keys = ws + off; off += (size_t)kB * kW * kHA;   // 6,291,456
  float* vals = ws + off; off += (size_t)kB * kW * kHA;
  float* att  = ws + off; off += (size_t)kB * kNV * kHA;  // 2,097,152
  float* tmp  = ws + off; off += (size_t)kB * kNV * kHA;
  float* ff1  = ws + off; off += (size_t)kB * kNV * kHA;
  float* ff2  = ws + off; off += (size_t)kB * kNV * kHA;
  float* logits = ws + off; off += (size_t)kB * kNV * kR;

  // 1. build ki
  {
    int total = kB * kW * 257;
    build_ki_kernel<<<(total + 255) / 256, 256, 0, stream>>>(hist, hist_u, pred,
                                                             pred_u, ki);
  }
  // 2. att = pred @ ds_w + ds_b  [4096, 512]
  gemm_bias_kernel<false><<<dim3(kHA / 64, (kB * kNV) / 64), 256, 0, stream>>>(
      pred, ds_w, ds_b, att, kB * kNV, kHA, kD);

  for (int l = 0; l < kL; ++l) {
    // per-layer weight repack, then keys/vals GEMMs [12288, 512] K=257
    repack_w_kernel<<<(257 * kHA + 255) / 256, 256, 0, stream>>>(key_w, val_w,
                                                                 kwp, vwp, l);
    gemm_bias_kernel<false><<<dim3(kHA / 64, (kB * kW) / 64), 256, 0, stream>>>(
        ki, kwp, key_b + l * kHA, keys, kB * kW, kHA, 257);
    gemm_bias_kernel<false><<<dim3(kHA / 64, (kB * kW) / 64), 256, 0, stream>>>(
        ki, vwp, val_b + l * kHA, vals, kB * kW, kHA, 257);
    // attention
    attn_kernel<<<dim3(2, kH, kB), 128, 0, stream>>>(att, keys, vals, tmp);
    add_ln_kernel<<<kB * kNV, 256, 0, stream>>>(att, tmp, ln1_g + l * kHA,
                                                ln1_b + l * kHA);
    // feed-forward
    gemm_bias_kernel<true><<<dim3(kM / 64, (kB * kNV) / 64), 256, 0, stream>>>(
        att, ff_w1 + (size_t)l * kHA * kM, ff_b1 + l * kM, ff1, kB * kNV, kM, kHA);
    gemm_bias_kernel<true><<<dim3(kM / 64, (kB * kNV) / 64), 256, 0, stream>>>(
        ff1, ff_w2 + (size_t)l * kM * kM, ff_b2 + l * kM, ff2, kB * kNV, kM, kM);
    gemm_bias_kernel<false><<<dim3(kHA / 64, (kB * kNV) / 64), 256, 0, stream>>>(
        ff2, ff_w3 + (size_t)l * kM * kHA, ff_b3 + l * kHA, tmp, kB * kNV, kHA, kM);
    add_ln_kernel<<<kB * kNV, 256, 0, stream>>>(att, tmp, ln2_g + l * kHA,
                                                ln2_b + l * kHA);
  }
  // de projection + loss
  gemm_bias_kernel<false><<<dim3(kR / 64, (kB * kNV) / 64), 256, 0, stream>>>(
      att, de_w, de_b, logits, kB * kNV, kR, kHA);
  loss_kernel<<<kB, 256, 0, stream>>>(logits, pred_u, out);
}

// Round 2
// 2326.322 us; speedup vs baseline: 2.0382x; 2.0382x over previous
//
#include <hip/hip_runtime.h>

// Problem constants (AttentionalCopula)
constexpr int kB = 16, kD = 256, kNH = 512, kNV = 256, kW = 768;
constexpr int kL = 4, kH = 8, kA = 64, kHA = 512, kM = 512, kR = 128;

// ---------------- build ki = [hist||u ; pred||u] : [B, W, 257] ----------------
__global__ void build_ki_kernel(const float* __restrict__ hist,
                                const float* __restrict__ hist_u,
                                const float* __restrict__ pred,
                                const float* __restrict__ pred_u,
                                float* __restrict__ ki) {
  int i = blockIdx.x * 256 + threadIdx.x;
  const int total = kB * kW * 257;
  if (i >= total) return;
  int d = i % 257;
  int bw = i / 257;
  int w = bw % kW;
  int b = bw / kW;
  float v;
  if (w < kNH) {
    v = (d < kD) ? hist[((size_t)b * kNH + w) * kD + d] : hist_u[b * kNH + w];
  } else {
    int p = w - kNH;
    v = (d < kD) ? pred[((size_t)b * kNV + p) * kD + d] : pred_u[b * kNV + p];
  }
  ki[i] = v;
}

// ------------- repack key/val weights for layer l: [H,257,A] -> [257, H*A] -------------
__global__ void repack_w_kernel(const float* __restrict__ kw,
                                const float* __restrict__ vw,
                                float* __restrict__ kwp,
                                float* __restrict__ vwp, int l) {
  int i = blockIdx.x * 256 + threadIdx.x;
  const int total = 257 * kHA;
  if (i >= total) return;
  int col = i % kHA;  // h*64 + a
  int d = i / kHA;
  int h = col / kA;
  int a = col % kA;
  size_t src = (((size_t)l * kH + h) * 257 + d) * kA + a;
  kwp[i] = kw[src];
  vwp[i] = vw[src];
}

// ---------------- fp32 GEMM: C[M,N] = A[M,K] @ B[K,N] + bias (opt relu) ----------------
template <bool RELU>
__global__ __launch_bounds__(256) void gemm_bias_kernel(
    const float* __restrict__ A, const float* __restrict__ Bm,
    const float* __restrict__ bias, float* __restrict__ C,
    int M, int N, int K) {
  __shared__ float As[16][68];
  __shared__ float Bs[16][68];
  const int tx = threadIdx.x & 15;
  const int ty = threadIdx.x >> 4;
  const int bm = blockIdx.y * 64;
  const int bn = blockIdx.x * 64;
  float acc[4][4] = {};
  for (int k0 = 0; k0 < K; k0 += 16) {
    for (int i = threadIdx.x; i < 1024; i += 256) {
      int m = i >> 4, k = i & 15;
      float v = 0.f;
      if (k0 + k < K) v = A[(size_t)(bm + m) * K + k0 + k];
      As[k][m] = v;
    }
    for (int i = threadIdx.x; i < 1024; i += 256) {
      int k = i >> 6, n = i & 63;
      float v = 0.f;
      if (k0 + k < K) v = Bm[(size_t)(k0 + k) * N + bn + n];
      Bs[k][n] = v;
    }
    __syncthreads();
#pragma unroll
    for (int kk = 0; kk < 16; ++kk) {
      float4 av = *(const float4*)&As[kk][ty * 4];
      float4 bv = *(const float4*)&Bs[kk][tx * 4];
      float a_[4] = {av.x, av.y, av.z, av.w};
      float b_[4] = {bv.x, bv.y, bv.z, bv.w};
#pragma unroll
      for (int i = 0; i < 4; ++i)
#pragma unroll
        for (int j = 0; j < 4; ++j) acc[i][j] += a_[i] * b_[j];
    }
    __syncthreads();
  }
#pragma unroll
  for (int i = 0; i < 4; ++i) {
    int m = bm + ty * 4 + i;
    int n0 = bn + tx * 4;
    float4 o;
    o.x = acc[i][0] + bias[n0 + 0];
    o.y = acc[i][1] + bias[n0 + 1];
    o.z = acc[i][2] + bias[n0 + 2];
    o.w = acc[i][3] + bias[n0 + 3];
    if (RELU) {
      o.x = fmaxf(o.x, 0.f); o.y = fmaxf(o.y, 0.f);
      o.z = fmaxf(o.z, 0.f); o.w = fmaxf(o.w, 0.f);
    }
    *(float4*)&C[(size_t)m * N + n0] = o;
  }
}

// ---------------- tiled flash attention ----------------
// Block = 256 threads handles one (b, h, 64-query tile).
// S=QK^T via 4x4-register GEMM from LDS (Q,K stored d-major: conflict-free b128),
// online softmax with 16-lane shfl row reductions, P->LDS, O += P@V as second
// register GEMM. Masked chunks skipped: block qt runs 9+qt of 12 chunks.
__global__ __launch_bounds__(256) void attn_kernel(
    const float* __restrict__ att, const float* __restrict__ keys,
    const float* __restrict__ vals, float* __restrict__ out) {
  const int b = blockIdx.z, h = blockIdx.y, qt = blockIdx.x;
  __shared__ float Qs[64][64];  // [d][q]
  __shared__ float Ks[64][64];  // [d][p]
  __shared__ float Vs[64][68];  // [p][d]
  __shared__ float Ps[64][68];  // [q][p]
  const int t = threadIdx.x;
  const int tx = t & 15, ty = t >> 4;
  const int rr = t >> 2;         // staging row 0..63
  const int dc = (t & 3) * 16;   // staging d-offset
  // stage Q transposed [d][q]
  {
    const float* qp = att + ((size_t)(b * kNV + qt * 64 + rr) * kHA + h * kA + dc);
#pragma unroll
    for (int k4 = 0; k4 < 4; ++k4) {
      float4 v = *(const float4*)(qp + k4 * 4);
      Qs[dc + k4 * 4 + 0][rr] = v.x;
      Qs[dc + k4 * 4 + 1][rr] = v.y;
      Qs[dc + k4 * 4 + 2][rr] = v.z;
      Qs[dc + k4 * 4 + 3][rr] = v.w;
    }
  }
  float o[4][4] = {};
  float m_[4] = {-1e30f, -1e30f, -1e30f, -1e30f};
  float l_[4] = {0.f, 0.f, 0.f, 0.f};
  const int cmax = kNH + qt * 64;
  for (int c0 = 0; c0 <= cmax; c0 += 64) {
    const float* kp = keys + ((size_t)(b * kW + c0 + rr) * kHA + h * kA + dc);
    const float* vp = vals + ((size_t)(b * kW + c0 + rr) * kHA + h * kA + dc);
    float4 kreg[4], vreg[4];
#pragma unroll
    for (int k4 = 0; k4 < 4; ++k4) {
      kreg[k4] = *(const float4*)(kp + k4 * 4);
      vreg[k4] = *(const float4*)(vp + k4 * 4);
    }
    __syncthreads();  // previous chunk's LDS reads complete
#pragma unroll
    for (int k4 = 0; k4 < 4; ++k4) {
      Ks[dc + k4 * 4 + 0][rr] = kreg[k4].x;
      Ks[dc + k4 * 4 + 1][rr] = kreg[k4].y;
      Ks[dc + k4 * 4 + 2][rr] = kreg[k4].z;
      Ks[dc + k4 * 4 + 3][rr] = kreg[k4].w;
      *(float4*)&Vs[rr][dc + k4 * 4] = vreg[k4];
    }
    __syncthreads();
    // ---- S = Q @ K^T (64x64 tile, 4x4 per thread) ----
    float s[4][4] = {};
#pragma unroll 4
    for (int d = 0; d < 64; ++d) {
      float4 qv = *(const float4*)&Qs[d][ty * 4];
      float4 kv = *(const float4*)&Ks[d][tx * 4];
      float qa[4] = {qv.x, qv.y, qv.z, qv.w};
      float ka[4] = {kv.x, kv.y, kv.z, kv.w};
#pragma unroll
      for (int i = 0; i < 4; ++i)
#pragma unroll
        for (int j = 0; j < 4; ++j) s[i][j] += qa[i] * ka[j];
    }
    // ---- mask + scale + online softmax (rows spread over 16 tx lanes) ----
    const int lim = cmax - c0;  // valid iff p_local < lim + q_local
#pragma unroll
    for (int i = 0; i < 4; ++i) {
#pragma unroll
      for (int j = 0; j < 4; ++j)
        s[i][j] = (tx * 4 + j < lim + ty * 4 + i) ? s[i][j] * 0.125f : -1e30f;
      float mx = fmaxf(fmaxf(s[i][0], s[i][1]), fmaxf(s[i][2], s[i][3]));
      mx = fmaxf(mx, __shfl_xor(mx, 1));
      mx = fmaxf(mx, __shfl_xor(mx, 2));
      mx = fmaxf(mx, __shfl_xor(mx, 4));
      mx = fmaxf(mx, __shfl_xor(mx, 8));
      float mnew = fmaxf(m_[i], mx);
      float corr = __expf(m_[i] - mnew);
      float rs = 0.f;
#pragma unroll
      for (int j = 0; j < 4; ++j) {
        s[i][j] = __expf(s[i][j] - mnew);
        rs += s[i][j];
      }
      rs += __shfl_xor(rs, 1);
      rs += __shfl_xor(rs, 2);
      rs += __shfl_xor(rs, 4);
      rs += __shfl_xor(rs, 8);
      l_[i] = l_[i] * corr + rs;
      m_[i] = mnew;
#pragma unroll
      for (int j = 0; j < 4; ++j) o[i][j] *= corr;
      *(float4*)&Ps[ty * 4 + i][tx * 4] =
          make_float4(s[i][0], s[i][1], s[i][2], s[i][3]);
    }
    __syncthreads();
    // ---- O += P @ V (4x4 per thread) ----
#pragma unroll 2
    for (int p0 = 0; p0 < 64; p0 += 4) {
      float4 pv[4];
#pragma unroll
      for (int i = 0; i < 4; ++i) pv[i] = *(const float4*)&Ps[ty * 4 + i][p0];
#pragma unroll
      for (int k = 0; k < 4; ++k) {
        float4 vv = *(const float4*)&Vs[p0 + k][tx * 4];
#pragma unroll
        for (int i = 0; i < 4; ++i) {
          float pc = (&pv[i].x)[k];
          o[i][0] += pc * vv.x;
          o[i][1] += pc * vv.y;
          o[i][2] += pc * vv.z;
          o[i][3] += pc * vv.w;
        }
      }
    }
  }
  // ---- epilogue: normalize + store ----
#pragma unroll
  for (int i = 0; i < 4; ++i) {
    float inv = 1.f / l_[i];
    float4 ov = make_float4(o[i][0] * inv, o[i][1] * inv, o[i][2] * inv,
                            o[i][3] * inv);
    *(float4*)&out[(size_t)(b * kNV + qt * 64 + ty * 4 + i) * kHA + h * kA +
                   tx * 4] = ov;
  }
}

// ---------------- att = LN(att + add) * g + b, row width HA=512 ----------------
__global__ __launch_bounds__(256) void add_ln_kernel(
    float* __restrict__ att, const float* __restrict__ add,
    const float* __restrict__ g, const float* __restrict__ be) {
  const int row = blockIdx.x;
  const int t = threadIdx.x;
  float* ar = att + (size_t)row * kHA;
  const float* dr = add + (size_t)row * kHA;
  float x0 = ar[t] + dr[t];
  float x1 = ar[t + 256] + dr[t + 256];
  float s = x0 + x1, sq = x0 * x0 + x1 * x1;
  for (int off = 32; off; off >>= 1) {
    s += __shfl_down(s, off);
    sq += __shfl_down(sq, off);
  }
  __shared__ float ssum[4], ssq[4], stats[2];
  if ((t & 63) == 0) { ssum[t >> 6] = s; ssq[t >> 6] = sq; }
  __syncthreads();
  if (t == 0) {
    float S = ssum[0] + ssum[1] + ssum[2] + ssum[3];
    float Q = ssq[0] + ssq[1] + ssq[2] + ssq[3];
    float mean = S * (1.f / kHA);
    float var = Q * (1.f / kHA) - mean * mean;
    stats[0] = mean;
    stats[1] = rsqrtf(var + 1e-5f);
  }
  __syncthreads();
  float mean = stats[0], inv = stats[1];
  ar[t] = g[t] * (x0 - mean) * inv + be[t];
  ar[t + 256] = g[t + 256] * (x1 - mean) * inv + be[t + 256];
}

// ---------------- loss ----------------
__global__ __launch_bounds__(256) void loss_kernel(
    const float* __restrict__ logits, const float* __restrict__ pred_u,
    float* __restrict__ out) {
  const int b = blockIdx.x;
  const int t = threadIdx.x;
  float lp = 0.f;
  if (t >= 1) {
    const float* row = logits + (size_t)(b * kNV + t) * kR;
    float mx = -1e30f;
    for (int i = 0; i < kR; ++i) mx = fmaxf(mx, row[i]);
    float se = 0.f;
    for (int i = 0; i < kR; ++i) se += expf(row[i] - mx);
    float lse = mx + logf(se);
    float u = pred_u[b * kNV + t];
    int tgt = (int)floorf(u * (float)kR);
    tgt = max(0, min(kR - 1, tgt));
    lp = logf((float)kR) + row[tgt] - lse;
  }
  for (int off = 32; off; off >>= 1) lp += __shfl_down(lp, off);
  __shared__ float red[4];
  if ((t & 63) == 0) red[t >> 6] = lp;
  __syncthreads();
  if (t == 0) out[b] = -(red[0] + red[1] + red[2] + red[3]);
}

extern "C" void kernel_launch(void* const* d_in, const int* in_sizes, int n_in,
                              void* d_out, int out_size, void* d_ws, size_t ws_size,
                              hipStream_t stream) {
  const float* hist   = (const float*)d_in[0];
  const float* hist_u = (const float*)d_in[1];
  const float* pred   = (const float*)d_in[2];
  const float* pred_u = (const float*)d_in[3];
  const float* ds_w   = (const float*)d_in[4];
  const float* ds_b   = (const float*)d_in[5];
  const float* key_w  = (const float*)d_in[6];
  const float* key_b  = (const float*)d_in[7];
  const float* val_w  = (const float*)d_in[8];
  const float* val_b  = (const float*)d_in[9];
  const float* ln1_g  = (const float*)d_in[10];
  const float* ln1_b  = (const float*)d_in[11];
  const float* ln2_g  = (const float*)d_in[12];
  const float* ln2_b  = (const float*)d_in[13];
  const float* ff_w1  = (const float*)d_in[14];
  const float* ff_b1  = (const float*)d_in[15];
  const float* ff_w2  = (const float*)d_in[16];
  const float* ff_b2  = (const float*)d_in[17];
  const float* ff_w3  = (const float*)d_in[18];
  const float* ff_b3  = (const float*)d_in[19];
  const float* de_w   = (const float*)d_in[20];
  const float* de_b   = (const float*)d_in[21];
  float* out = (float*)d_out;

  float* ws = (float*)d_ws;
  size_t off = 0;
  float* ki   = ws + off; off += (size_t)kB * kW * 257;
  float* kwp  = ws + off; off += (size_t)257 * kHA;
  float* vwp  = ws + off; off += (size_t)257 * kHA;
  float* keys = ws + off; off += (size_t)kB * kW * kHA;
  float* vals = ws + off; off += (size_t)kB * kW * kHA;
  float* att  = ws + off; off += (size_t)kB * kNV * kHA;
  float* tmp  = ws + off; off += (size_t)kB * kNV * kHA;
  float* ff1  = ws + off; off += (size_t)kB * kNV * kHA;
  float* ff2  = ws + off; off += (size_t)kB * kNV * kHA;
  float* logits = ws + off; off += (size_t)kB * kNV * kR;

  {
    int total = kB * kW * 257;
    build_ki_kernel<<<(total + 255) / 256, 256, 0, stream>>>(hist, hist_u, pred,
                                                             pred_u, ki);
  }
  gemm_bias_kernel<false><<<dim3(kHA / 64, (kB * kNV) / 64), 256, 0, stream>>>(
      pred, ds_w, ds_b, att, kB * kNV, kHA, kD);

  for (int l = 0; l < kL; ++l) {
    repack_w_kernel<<<(257 * kHA + 255) / 256, 256, 0, stream>>>(key_w, val_w,
                                                                 kwp, vwp, l);
    gemm_bias_kernel<false><<<dim3(kHA / 64, (kB * kW) / 64), 256, 0, stream>>>(
        ki, kwp, key_b + l * kHA, keys, kB * kW, kHA, 257);
    gemm_bias_kernel<false><<<dim3(kHA / 64, (kB * kW) / 64), 256, 0, stream>>>(
        ki, vwp, val_b + l * kHA, vals, kB * kW, kHA, 257);
    attn_kernel<<<dim3(kNV / 64, kH, kB), 256, 0, stream>>>(att, keys, vals, tmp);
    add_ln_kernel<<<kB * kNV, 256, 0, stream>>>(att, tmp, ln1_g + l * kHA,
                                                ln1_b + l * kHA);
    gemm_bias_kernel<true><<<dim3(kM / 64, (kB * kNV) / 64), 256, 0, stream>>>(
        att, ff_w1 + (size_t)l * kHA * kM, ff_b1 + l * kM, ff1, kB * kNV, kM, kHA);
    gemm_bias_kernel<true><<<dim3(kM / 64, (kB * kNV) / 64), 256, 0, stream>>>(
        ff1, ff_w2 + (size_t)l * kM * kM, ff_b2 + l * kM, ff2, kB * kNV, kM, kM);
    gemm_bias_kernel<false><<<dim3(kHA / 64, (kB * kNV) / 64), 256, 0, stream>>>(
        ff2, ff_w3 + (size_t)l * kM * kHA, ff_b3 + l * kHA, tmp, kB * kNV, kHA, kM);
    add_ln_kernel<<<kB * kNV, 256, 0, stream>>>(att, tmp, ln2_g + l * kHA,
                                                ln2_b + l * kHA);
  }
  gemm_bias_kernel<false><<<dim3(kR / 64, (kB * kNV) / 64), 256, 0, stream>>>(
      att, de_w, de_b, logits, kB * kNV, kR, kHA);
  loss_kernel<<<kB, 256, 0, stream>>>(logits, pred_u, out);
}

// Round 3
// 844.760 us; speedup vs baseline: 5.6128x; 2.7538x over previous
//
#include <hip/hip_runtime.h>

// Problem constants (AttentionalCopula)
constexpr int kB = 16, kD = 256, kNH = 512, kNV = 256, kW = 768;
constexpr int kL = 4, kH = 8, kA = 64, kHA = 512, kM = 512, kR = 128;
constexpr int kKP = 288;  // K=257 zero-padded to multiple of 32

typedef __bf16 bf16x8 __attribute__((ext_vector_type(8)));
typedef float f32x4 __attribute__((ext_vector_type(4)));

__device__ inline void load_lds16(const __bf16* g, __bf16* l) {
  __builtin_amdgcn_global_load_lds(
      (const __attribute__((address_space(1))) void*)g,
      (__attribute__((address_space(3))) void*)l, 16, 0, 0);
}

// ---------------- prep kernels (run every call; all outputs fully written) ----------------
__global__ void build_ki_bf_kernel(const float* __restrict__ hist,
                                   const float* __restrict__ hist_u,
                                   const float* __restrict__ pred,
                                   const float* __restrict__ pred_u,
                                   __bf16* __restrict__ ki) {
  int i = blockIdx.x * 256 + threadIdx.x;
  const int total = kB * kW * kKP;
  if (i >= total) return;
  int d = i % kKP;
  int bw = i / kKP;
  int w = bw % kW;
  int b = bw / kW;
  float v = 0.f;
  if (d < 257) {
    if (w < kNH)
      v = (d < kD) ? hist[((size_t)b * kNH + w) * kD + d] : hist_u[b * kNH + w];
    else {
      int p = w - kNH;
      v = (d < kD) ? pred[((size_t)b * kNV + p) * kD + d] : pred_u[b * kNV + p];
    }
  }
  ki[i] = (__bf16)v;
}

__global__ void conv_pred_kernel(const float* __restrict__ pred,
                                 __bf16* __restrict__ out) {
  int i = blockIdx.x * 256 + threadIdx.x;
  if (i < kB * kNV * kD) out[i] = (__bf16)pred[i];
}

// kv weights -> [L][1024][288] bf16, transposed+padded. col c = kv*512+h*64+a
__global__ void conv_kvw_kernel(const float* __restrict__ kw,
                                const float* __restrict__ vw,
                                __bf16* __restrict__ kvwt) {
  int i = blockIdx.x * 256 + threadIdx.x;
  const int total = kL * 1024 * kKP;
  if (i >= total) return;
  int d = i % kKP;
  int c = (i / kKP) & 1023;
  int l = i / (kKP * 1024);
  float v = 0.f;
  if (d < 257) {
    int kvv = c >> 9, h = (c >> 6) & 7, a = c & 63;
    size_t src = (((size_t)l * kH + h) * 257 + d) * kA + a;
    v = kvv ? vw[src] : kw[src];
  }
  kvwt[i] = (__bf16)v;
}

// ff weights [L][512][512]x3 -> transposed bf16 [12][512n][512k]
__global__ void conv_ffw_kernel(const float* __restrict__ w1,
                                const float* __restrict__ w2,
                                const float* __restrict__ w3,
                                __bf16* __restrict__ out) {
  int i = blockIdx.x * 256 + threadIdx.x;
  const int total = 12 * 512 * 512;
  if (i >= total) return;
  int k = i & 511;
  int n = (i >> 9) & 511;
  int mat = i >> 18;
  int l = mat / 3, which = mat % 3;
  const float* src = which == 0 ? w1 : which == 1 ? w2 : w3;
  out[i] = (__bf16)src[((size_t)l * 512 + k) * 512 + n];
}

// ds_wt [512][256], de_wt [128][512], kv bias pack [L][1024]
__global__ void conv_misc_kernel(const float* __restrict__ ds_w,
                                 const float* __restrict__ de_w,
                                 const float* __restrict__ key_b,
                                 const float* __restrict__ val_b,
                                 __bf16* __restrict__ ds_wt,
                                 __bf16* __restrict__ de_wt,
                                 float* __restrict__ kvb) {
  int i = blockIdx.x * 256 + threadIdx.x;
  if (i < 131072) {
    int n = i >> 8, k = i & 255;
    ds_wt[i] = (__bf16)ds_w[k * 512 + n];
  } else if (i < 196608) {
    int j = i - 131072;
    int n = j >> 9, k = j & 511;
    de_wt[j] = (__bf16)de_w[k * 128 + n];
  } else if (i < 200704) {
    int j = i - 196608;
    int l = j >> 10, c = j & 1023;
    kvb[j] = (c < 512) ? key_b[l * 512 + c] : val_b[l * 512 + (c - 512)];
  }
}

// ---------------- bf16 MFMA GEMM (m97 structure) ----------------
// C[M,N] = A[M,K]@B[K,N] + bias; Bt is B transposed [N][K]. 128x128 tile,
// BK=32, 4 waves in 2x2, each wave 64x64 = 4x4 MFMA 16x16x32 tiles.
template <bool OUT_BF16, bool RELU>
__global__ __launch_bounds__(256) void gemm_mfma_kernel(
    const __bf16* __restrict__ A, const __bf16* __restrict__ Bt,
    const float* __restrict__ bias, void* __restrict__ Cout,
    int M, int N, int K) {
  __shared__ __bf16 As[128 * 32];
  __shared__ __bf16 Bs[128 * 32];
  const int t = threadIdx.x;
  const int wid = t >> 6;
  const int lane = t & 63;
  const int bm = blockIdx.y * 128;
  const int bn = blockIdx.x * 128;
  const int wm = (wid >> 1) * 64;
  const int wn = (wid & 1) * 64;
  // staging: wave wid covers rows [wid*32, wid*32+32) of both tiles
  const int sr = lane >> 2, sc = lane & 3;
  const __bf16* Ag = A + (size_t)(bm + wid * 32 + sr) * K + sc * 8;
  const __bf16* Bg = Bt + (size_t)(bn + wid * 32 + sr) * K + sc * 8;
  __bf16* AsW = As + (wid * 32) * 32;
  __bf16* BsW = Bs + (wid * 32) * 32;

  f32x4 acc[4][4] = {};
  const int q = lane >> 4, mr = lane & 15;
  for (int k0 = 0; k0 < K; k0 += 32) {
    if (k0) __syncthreads();
#pragma unroll
    for (int j = 0; j < 2; ++j) {
      load_lds16(Ag + (size_t)(j * 16) * K + k0, AsW + j * 16 * 32);
      load_lds16(Bg + (size_t)(j * 16) * K + k0, BsW + j * 16 * 32);
    }
    __syncthreads();  // drains vmcnt(0) then barrier
    bf16x8 af[4], bfr[4];
#pragma unroll
    for (int i = 0; i < 4; ++i) {
      af[i] = *(const bf16x8*)(As + (wm + i * 16 + mr) * 32 + q * 8);
      bfr[i] = *(const bf16x8*)(Bs + (wn + i * 16 + mr) * 32 + q * 8);
    }
#pragma unroll
    for (int i = 0; i < 4; ++i)
#pragma unroll
      for (int j = 0; j < 4; ++j)
        acc[i][j] = __builtin_amdgcn_mfma_f32_16x16x32_bf16(af[i], bfr[j],
                                                            acc[i][j], 0, 0, 0);
  }
  // epilogue: D lane mapping col=lane&15, row=quad*4+reg
#pragma unroll
  for (int j = 0; j < 4; ++j) {
    int col = bn + wn + j * 16 + mr;
    float bs = bias[col];
#pragma unroll
    for (int i = 0; i < 4; ++i) {
      int row0 = bm + wm + i * 16 + q * 4;
#pragma unroll
      for (int r = 0; r < 4; ++r) {
        float v = acc[i][j][r] + bs;
        if (RELU) v = fmaxf(v, 0.f);
        if (OUT_BF16)
          ((__bf16*)Cout)[(size_t)(row0 + r) * N + col] = (__bf16)v;
        else
          ((float*)Cout)[(size_t)(row0 + r) * N + col] = v;
      }
    }
  }
}

// ---------------- tiled flash attention (K/V in bf16, row stride 1024) ----------------
__global__ __launch_bounds__(256) void attn_kernel(
    const float* __restrict__ att, const __bf16* __restrict__ kv,
    float* __restrict__ out) {
  const int b = blockIdx.z, h = blockIdx.y, qt = blockIdx.x;
  __shared__ float Qs[64][64];  // [d][q]
  __shared__ float Ks[64][64];  // [d][p]
  __shared__ float Vs[64][68];  // [p][d]
  __shared__ float Ps[64][68];  // [q][p]
  const int t = threadIdx.x;
  const int tx = t & 15, ty = t >> 4;
  const int rr = t >> 2;
  const int dc = (t & 3) * 16;
  {
    const float* qp = att + ((size_t)(b * kNV + qt * 64 + rr) * kHA + h * kA + dc);
#pragma unroll
    for (int k4 = 0; k4 < 4; ++k4) {
      float4 v = *(const float4*)(qp + k4 * 4);
      Qs[dc + k4 * 4 + 0][rr] = v.x;
      Qs[dc + k4 * 4 + 1][rr] = v.y;
      Qs[dc + k4 * 4 + 2][rr] = v.z;
      Qs[dc + k4 * 4 + 3][rr] = v.w;
    }
  }
  float o[4][4] = {};
  float m_[4] = {-1e30f, -1e30f, -1e30f, -1e30f};
  float l_[4] = {0.f, 0.f, 0.f, 0.f};
  const int cmax = kNH + qt * 64;
  for (int c0 = 0; c0 <= cmax; c0 += 64) {
    const __bf16* kp = kv + ((size_t)(b * kW + c0 + rr) * 1024 + h * kA + dc);
    bf16x8 k0v = *(const bf16x8*)kp;
    bf16x8 k1v = *(const bf16x8*)(kp + 8);
    bf16x8 v0v = *(const bf16x8*)(kp + 512);
    bf16x8 v1v = *(const bf16x8*)(kp + 520);
    __syncthreads();
#pragma unroll
    for (int e = 0; e < 8; ++e) {
      Ks[dc + e][rr] = (float)k0v[e];
      Ks[dc + 8 + e][rr] = (float)k1v[e];
    }
    *(float4*)&Vs[rr][dc] =
        make_float4((float)v0v[0], (float)v0v[1], (float)v0v[2], (float)v0v[3]);
    *(float4*)&Vs[rr][dc + 4] =
        make_float4((float)v0v[4], (float)v0v[5], (float)v0v[6], (float)v0v[7]);
    *(float4*)&Vs[rr][dc + 8] =
        make_float4((float)v1v[0], (float)v1v[1], (float)v1v[2], (float)v1v[3]);
    *(float4*)&Vs[rr][dc + 12] =
        make_float4((float)v1v[4], (float)v1v[5], (float)v1v[6], (float)v1v[7]);
    __syncthreads();
    float s[4][4] = {};
#pragma unroll 4
    for (int d = 0; d < 64; ++d) {
      float4 qv = *(const float4*)&Qs[d][ty * 4];
      float4 kvv = *(const float4*)&Ks[d][tx * 4];
      float qa[4] = {qv.x, qv.y, qv.z, qv.w};
      float ka[4] = {kvv.x, kvv.y, kvv.z, kvv.w};
#pragma unroll
      for (int i = 0; i < 4; ++i)
#pragma unroll
        for (int j = 0; j < 4; ++j) s[i][j] += qa[i] * ka[j];
    }
    const int lim = cmax - c0;
#pragma unroll
    for (int i = 0; i < 4; ++i) {
#pragma unroll
      for (int j = 0; j < 4; ++j)
        s[i][j] = (tx * 4 + j < lim + ty * 4 + i) ? s[i][j] * 0.125f : -1e30f;
      float mx = fmaxf(fmaxf(s[i][0], s[i][1]), fmaxf(s[i][2], s[i][3]));
      mx = fmaxf(mx, __shfl_xor(mx, 1));
      mx = fmaxf(mx, __shfl_xor(mx, 2));
      mx = fmaxf(mx, __shfl_xor(mx, 4));
      mx = fmaxf(mx, __shfl_xor(mx, 8));
      float mnew = fmaxf(m_[i], mx);
      float corr = __expf(m_[i] - mnew);
      float rs = 0.f;
#pragma unroll
      for (int j = 0; j < 4; ++j) {
        s[i][j] = __expf(s[i][j] - mnew);
        rs += s[i][j];
      }
      rs += __shfl_xor(rs, 1);
      rs += __shfl_xor(rs, 2);
      rs += __shfl_xor(rs, 4);
      rs += __shfl_xor(rs, 8);
      l_[i] = l_[i] * corr + rs;
      m_[i] = mnew;
#pragma unroll
      for (int j = 0; j < 4; ++j) o[i][j] *= corr;
      *(float4*)&Ps[ty * 4 + i][tx * 4] =
          make_float4(s[i][0], s[i][1], s[i][2], s[i][3]);
    }
    __syncthreads();
#pragma unroll 2
    for (int p0 = 0; p0 < 64; p0 += 4) {
      float4 pv[4];
#pragma unroll
      for (int i = 0; i < 4; ++i) pv[i] = *(const float4*)&Ps[ty * 4 + i][p0];
#pragma unroll
      for (int k = 0; k < 4; ++k) {
        float4 vv = *(const float4*)&Vs[p0 + k][tx * 4];
#pragma unroll
        for (int i = 0; i < 4; ++i) {
          float pc = (&pv[i].x)[k];
          o[i][0] += pc * vv.x;
          o[i][1] += pc * vv.y;
          o[i][2] += pc * vv.z;
          o[i][3] += pc * vv.w;
        }
      }
    }
  }
#pragma unroll
  for (int i = 0; i < 4; ++i) {
    float inv = 1.f / l_[i];
    float4 ov = make_float4(o[i][0] * inv, o[i][1] * inv, o[i][2] * inv,
                            o[i][3] * inv);
    *(float4*)&out[(size_t)(b * kNV + qt * 64 + ty * 4 + i) * kHA + h * kA +
                   tx * 4] = ov;
  }
}

// ---------------- att = LN(att + add); also emits bf16 copy ----------------
__global__ __launch_bounds__(256) void add_ln_kernel(
    float* __restrict__ att, const float* __restrict__ add,
    const float* __restrict__ g, const float* __restrict__ be,
    __bf16* __restrict__ attbf) {
  const int row = blockIdx.x;
  const int t = threadIdx.x;
  float* ar = att + (size_t)row * kHA;
  const float* dr = add + (size_t)row * kHA;
  float x0 = ar[t] + dr[t];
  float x1 = ar[t + 256] + dr[t + 256];
  float s = x0 + x1, sq = x0 * x0 + x1 * x1;
  for (int off = 32; off; off >>= 1) {
    s += __shfl_down(s, off);
    sq += __shfl_down(sq, off);
  }
  __shared__ float ssum[4], ssq[4], stats[2];
  if ((t & 63) == 0) { ssum[t >> 6] = s; ssq[t >> 6] = sq; }
  __syncthreads();
  if (t == 0) {
    float S = ssum[0] + ssum[1] + ssum[2] + ssum[3];
    float Q = ssq[0] + ssq[1] + ssq[2] + ssq[3];
    float mean = S * (1.f / kHA);
    float var = Q * (1.f / kHA) - mean * mean;
    stats[0] = mean;
    stats[1] = rsqrtf(var + 1e-5f);
  }
  __syncthreads();
  float mean = stats[0], inv = stats[1];
  float y0 = g[t] * (x0 - mean) * inv + be[t];
  float y1 = g[t + 256] * (x1 - mean) * inv + be[t + 256];
  ar[t] = y0;
  ar[t + 256] = y1;
  attbf[(size_t)row * kHA + t] = (__bf16)y0;
  attbf[(size_t)row * kHA + t + 256] = (__bf16)y1;
}

// ---------------- loss ----------------
__global__ __launch_bounds__(256) void loss_kernel(
    const float* __restrict__ logits, const float* __restrict__ pred_u,
    float* __restrict__ out) {
  const int b = blockIdx.x;
  const int t = threadIdx.x;
  float lp = 0.f;
  if (t >= 1) {
    const float* row = logits + (size_t)(b * kNV + t) * kR;
    float mx = -1e30f;
    for (int i = 0; i < kR; ++i) mx = fmaxf(mx, row[i]);
    float se = 0.f;
    for (int i = 0; i < kR; ++i) se += expf(row[i] - mx);
    float lse = mx + logf(se);
    float u = pred_u[b * kNV + t];
    int tgt = (int)floorf(u * (float)kR);
    tgt = max(0, min(kR - 1, tgt));
    lp = logf((float)kR) + row[tgt] - lse;
  }
  for (int off = 32; off; off >>= 1) lp += __shfl_down(lp, off);
  __shared__ float red[4];
  if ((t & 63) == 0) red[t >> 6] = lp;
  __syncthreads();
  if (t == 0) out[b] = -(red[0] + red[1] + red[2] + red[3]);
}

extern "C" void kernel_launch(void* const* d_in, const int* in_sizes, int n_in,
                              void* d_out, int out_size, void* d_ws, size_t ws_size,
                              hipStream_t stream) {
  const float* hist   = (const float*)d_in[0];
  const float* hist_u = (const float*)d_in[1];
  const float* pred   = (const float*)d_in[2];
  const float* pred_u = (const float*)d_in[3];
  const float* ds_w   = (const float*)d_in[4];
  const float* ds_b   = (const float*)d_in[5];
  const float* key_w  = (const float*)d_in[6];
  const float* key_b  = (const float*)d_in[7];
  const float* val_w  = (const float*)d_in[8];
  const float* val_b  = (const float*)d_in[9];
  const float* ln1_g  = (const float*)d_in[10];
  const float* ln1_b  = (const float*)d_in[11];
  const float* ln2_g  = (const float*)d_in[12];
  const float* ln2_b  = (const float*)d_in[13];
  const float* ff_w1  = (const float*)d_in[14];
  const float* ff_b1  = (const float*)d_in[15];
  const float* ff_w2  = (const float*)d_in[16];
  const float* ff_b2  = (const float*)d_in[17];
  const float* ff_w3  = (const float*)d_in[18];
  const float* ff_b3  = (const float*)d_in[19];
  const float* de_w   = (const float*)d_in[20];
  const float* de_b   = (const float*)d_in[21];
  float* out = (float*)d_out;

  // workspace layout (bytes, all 16B-aligned)
  char* ws = (char*)d_ws;
  size_t off = 0;
  auto alloc = [&](size_t bytes) { char* p = ws + off; off += bytes; return p; };
  __bf16* ki_bf   = (__bf16*)alloc((size_t)kB * kW * kKP * 2);     // 7.1 MB
  __bf16* pred_bf = (__bf16*)alloc((size_t)kB * kNV * kD * 2);     // 2 MB
  __bf16* kv_wt   = (__bf16*)alloc((size_t)kL * 1024 * kKP * 2);   // 2.4 MB
  __bf16* ffw_t   = (__bf16*)alloc((size_t)12 * 512 * 512 * 2);    // 6.3 MB
  __bf16* ds_wt   = (__bf16*)alloc((size_t)512 * 256 * 2);
  __bf16* de_wt   = (__bf16*)alloc((size_t)128 * 512 * 2);
  float*  kvb     = (float*)alloc((size_t)kL * 1024 * 4);
  __bf16* kvs     = (__bf16*)alloc((size_t)kB * kW * 1024 * 2);    // 25 MB
  float*  att     = (float*)alloc((size_t)kB * kNV * kHA * 4);     // 8.4 MB
  __bf16* att_bf  = (__bf16*)alloc((size_t)kB * kNV * kHA * 2);
  float*  tmp     = (float*)alloc((size_t)kB * kNV * kHA * 4);
  __bf16* ff1_bf  = (__bf16*)alloc((size_t)kB * kNV * kM * 2);
  __bf16* ff2_bf  = (__bf16*)alloc((size_t)kB * kNV * kM * 2);
  float*  logits  = (float*)alloc((size_t)kB * kNV * kR * 4);

  // prep
  build_ki_bf_kernel<<<(kB * kW * kKP + 255) / 256, 256, 0, stream>>>(
      hist, hist_u, pred, pred_u, ki_bf);
  conv_pred_kernel<<<(kB * kNV * kD + 255) / 256, 256, 0, stream>>>(pred, pred_bf);
  conv_kvw_kernel<<<(kL * 1024 * kKP + 255) / 256, 256, 0, stream>>>(key_w, val_w,
                                                                     kv_wt);
  conv_ffw_kernel<<<(12 * 512 * 512 + 255) / 256, 256, 0, stream>>>(ff_w1, ff_w2,
                                                                    ff_w3, ffw_t);
  conv_misc_kernel<<<(200704 + 255) / 256, 256, 0, stream>>>(
      ds_w, de_w, key_b, val_b, ds_wt, de_wt, kvb);

  // att = pred @ ds_w + ds_b (fp32 out)
  gemm_mfma_kernel<false, false><<<dim3(kHA / 128, kB * kNV / 128), 256, 0,
                                   stream>>>(pred_bf, ds_wt, ds_b, att,
                                             kB * kNV, kHA, kD);

  for (int l = 0; l < kL; ++l) {
    // keys||vals for this layer: [12288, 1024] bf16
    gemm_mfma_kernel<true, false><<<dim3(1024 / 128, kB * kW / 128), 256, 0,
                                    stream>>>(ki_bf, kv_wt + (size_t)l * 1024 * kKP,
                                              kvb + l * 1024, kvs, kB * kW, 1024,
                                              kKP);
    attn_kernel<<<dim3(kNV / 64, kH, kB), 256, 0, stream>>>(att, kvs, tmp);
    add_ln_kernel<<<kB * kNV, 256, 0, stream>>>(att, tmp, ln1_g + l * kHA,
                                                ln1_b + l * kHA, att_bf);
    gemm_mfma_kernel<true, true><<<dim3(kM / 128, kB * kNV / 128), 256, 0,
                                   stream>>>(att_bf, ffw_t + (size_t)(l * 3) * 262144,
                                             ff_b1 + l * kM, ff1_bf, kB * kNV, kM,
                                             kHA);
    gemm_mfma_kernel<true, true><<<dim3(kM / 128, kB * kNV / 128), 256, 0,
                                   stream>>>(ff1_bf,
                                             ffw_t + (size_t)(l * 3 + 1) * 262144,
                                             ff_b2 + l * kM, ff2_bf, kB * kNV, kM,
                                             kM);
    gemm_mfma_kernel<false, false><<<dim3(kHA / 128, kB * kNV / 128), 256, 0,
                                     stream>>>(ff2_bf,
                                               ffw_t + (size_t)(l * 3 + 2) * 262144,
                                               ff_b3 + l * kHA, tmp, kB * kNV, kHA,
                                               kM);
    add_ln_kernel<<<kB * kNV, 256, 0, stream>>>(att, tmp, ln2_g + l * kHA,
                                                ln2_b + l * kHA, att_bf);
  }
  gemm_mfma_kernel<false, false><<<dim3(kR / 128, kB * kNV / 128), 256, 0,
                                   stream>>>(att_bf, de_wt, de_b, logits,
                                             kB * kNV, kR, kHA);
  loss_kernel<<<kB, 256, 0, stream>>>(logits, pred_u, out);
}

// Round 4
// 577.646 us; speedup vs baseline: 8.2083x; 1.4624x over previous
//
#include <hip/hip_runtime.h>

// Problem constants (AttentionalCopula)
constexpr int kB = 16, kD = 256, kNH = 512, kNV = 256, kW = 768;
constexpr int kL = 4, kH = 8, kA = 64, kHA = 512, kM = 512, kR = 128;
constexpr int kKP = 288;  // K=257 zero-padded to multiple of 32

typedef __bf16 bf16x8 __attribute__((ext_vector_type(8)));
typedef float f32x4 __attribute__((ext_vector_type(4)));

__device__ inline void load_lds16(const __bf16* g, __bf16* l) {
  __builtin_amdgcn_global_load_lds(
      (const __attribute__((address_space(1))) void*)g,
      (__attribute__((address_space(3))) void*)l, 16, 0, 0);
}

// ---------------- prep kernels ----------------
__global__ void build_ki_bf_kernel(const float* __restrict__ hist,
                                   const float* __restrict__ hist_u,
                                   const float* __restrict__ pred,
                                   const float* __restrict__ pred_u,
                                   __bf16* __restrict__ ki) {
  int i = blockIdx.x * 256 + threadIdx.x;
  const int total = kB * kW * kKP;
  if (i >= total) return;
  int d = i % kKP;
  int bw = i / kKP;
  int w = bw % kW;
  int b = bw / kW;
  float v = 0.f;
  if (d < 257) {
    if (w < kNH)
      v = (d < kD) ? hist[((size_t)b * kNH + w) * kD + d] : hist_u[b * kNH + w];
    else {
      int p = w - kNH;
      v = (d < kD) ? pred[((size_t)b * kNV + p) * kD + d] : pred_u[b * kNV + p];
    }
  }
  ki[i] = (__bf16)v;
}

__global__ void conv_pred_kernel(const float* __restrict__ pred,
                                 __bf16* __restrict__ out) {
  int i = blockIdx.x * 256 + threadIdx.x;
  if (i < kB * kNV * kD) out[i] = (__bf16)pred[i];
}

__global__ void conv_kvw_kernel(const float* __restrict__ kw,
                                const float* __restrict__ vw,
                                __bf16* __restrict__ kvwt) {
  int i = blockIdx.x * 256 + threadIdx.x;
  const int total = kL * 1024 * kKP;
  if (i >= total) return;
  int d = i % kKP;
  int c = (i / kKP) & 1023;
  int l = i / (kKP * 1024);
  float v = 0.f;
  if (d < 257) {
    int kvv = c >> 9, h = (c >> 6) & 7, a = c & 63;
    size_t src = (((size_t)l * kH + h) * 257 + d) * kA + a;
    v = kvv ? vw[src] : kw[src];
  }
  kvwt[i] = (__bf16)v;
}

__global__ void conv_ffw_kernel(const float* __restrict__ w1,
                                const float* __restrict__ w2,
                                const float* __restrict__ w3,
                                __bf16* __restrict__ out) {
  int i = blockIdx.x * 256 + threadIdx.x;
  const int total = 12 * 512 * 512;
  if (i >= total) return;
  int k = i & 511;
  int n = (i >> 9) & 511;
  int mat = i >> 18;
  int l = mat / 3, which = mat % 3;
  const float* src = which == 0 ? w1 : which == 1 ? w2 : w3;
  out[i] = (__bf16)src[((size_t)l * 512 + k) * 512 + n];
}

__global__ void conv_misc_kernel(const float* __restrict__ ds_w,
                                 const float* __restrict__ de_w,
                                 const float* __restrict__ key_b,
                                 const float* __restrict__ val_b,
                                 __bf16* __restrict__ ds_wt,
                                 __bf16* __restrict__ de_wt,
                                 float* __restrict__ kvb) {
  int i = blockIdx.x * 256 + threadIdx.x;
  if (i < 131072) {
    int n = i >> 8, k = i & 255;
    ds_wt[i] = (__bf16)ds_w[k * 512 + n];
  } else if (i < 196608) {
    int j = i - 131072;
    int n = j >> 9, k = j & 511;
    de_wt[j] = (__bf16)de_w[k * 128 + n];
  } else if (i < 200704) {
    int j = i - 196608;
    int l = j >> 10, c = j & 1023;
    kvb[j] = (c < 512) ? key_b[l * 512 + c] : val_b[l * 512 + (c - 512)];
  }
}

// ---------------- bf16 MFMA GEMM (m97 structure) ----------------
// OMODE: 0 = f32 out, 1 = bf16 out, 2 = both (Cout f32 + Cout2 bf16)
template <int OMODE, bool RELU>
__global__ __launch_bounds__(256) void gemm_mfma_kernel(
    const __bf16* __restrict__ A, const __bf16* __restrict__ Bt,
    const float* __restrict__ bias, void* __restrict__ Cout,
    __bf16* __restrict__ Cout2, int M, int N, int K) {
  __shared__ __bf16 As[128 * 32];
  __shared__ __bf16 Bs[128 * 32];
  const int t = threadIdx.x;
  const int wid = t >> 6;
  const int lane = t & 63;
  const int bm = blockIdx.y * 128;
  const int bn = blockIdx.x * 128;
  const int wm = (wid >> 1) * 64;
  const int wn = (wid & 1) * 64;
  const int sr = lane >> 2, sc = lane & 3;
  const __bf16* Ag = A + (size_t)(bm + wid * 32 + sr) * K + sc * 8;
  const __bf16* Bg = Bt + (size_t)(bn + wid * 32 + sr) * K + sc * 8;
  __bf16* AsW = As + (wid * 32) * 32;
  __bf16* BsW = Bs + (wid * 32) * 32;

  f32x4 acc[4][4] = {};
  const int q = lane >> 4, mr = lane & 15;
  for (int k0 = 0; k0 < K; k0 += 32) {
    if (k0) __syncthreads();
#pragma unroll
    for (int j = 0; j < 2; ++j) {
      load_lds16(Ag + (size_t)(j * 16) * K + k0, AsW + j * 16 * 32);
      load_lds16(Bg + (size_t)(j * 16) * K + k0, BsW + j * 16 * 32);
    }
    __syncthreads();
    bf16x8 af[4], bfr[4];
#pragma unroll
    for (int i = 0; i < 4; ++i) {
      af[i] = *(const bf16x8*)(As + (wm + i * 16 + mr) * 32 + q * 8);
      bfr[i] = *(const bf16x8*)(Bs + (wn + i * 16 + mr) * 32 + q * 8);
    }
#pragma unroll
    for (int i = 0; i < 4; ++i)
#pragma unroll
      for (int j = 0; j < 4; ++j)
        acc[i][j] = __builtin_amdgcn_mfma_f32_16x16x32_bf16(af[i], bfr[j],
                                                            acc[i][j], 0, 0, 0);
  }
#pragma unroll
  for (int j = 0; j < 4; ++j) {
    int col = bn + wn + j * 16 + mr;
    float bs = bias[col];
#pragma unroll
    for (int i = 0; i < 4; ++i) {
      int row0 = bm + wm + i * 16 + q * 4;
#pragma unroll
      for (int r = 0; r < 4; ++r) {
        float v = acc[i][j][r] + bs;
        if (RELU) v = fmaxf(v, 0.f);
        size_t idx = (size_t)(row0 + r) * N + col;
        if (OMODE == 0) {
          ((float*)Cout)[idx] = v;
        } else if (OMODE == 1) {
          ((__bf16*)Cout)[idx] = (__bf16)v;
        } else {
          ((float*)Cout)[idx] = v;
          Cout2[idx] = (__bf16)v;
        }
      }
    }
  }
}

// ---------------- MFMA flash attention ----------------
// Block = 256 threads (4 waves) per (b, h, 64-query tile). QK^T and PV via
// mfma_f32_16x16x32_bf16. Q fragments register-resident; K staged [p][d],
// V staged transposed [d][p] (72-elem padded rows); P round-trips through
// LDS wave-locally (wave w owns rows [16w,16w+16)).
__global__ __launch_bounds__(256) void attn_mfma_kernel(
    const __bf16* __restrict__ attbf, const __bf16* __restrict__ kv,
    float* __restrict__ out) {
  const int b = blockIdx.z, h = blockIdx.y, qt = blockIdx.x;
  __shared__ __bf16 Ks[64 * 72];
  __shared__ __bf16 Vt[64 * 72];
  __shared__ __bf16 Ps[64 * 72];
  const int t = threadIdx.x;
  const int w = t >> 6, lane = t & 63;
  const int quad = lane >> 4, mr = lane & 15;
  // Q fragments: A[m=mr][k=quad*8+e (+32)] for rows w*16+mr
  bf16x8 aq[2];
  {
    const __bf16* qp = attbf + ((size_t)(b * kNV + qt * 64 + w * 16 + mr) * kHA +
                                h * kA + quad * 8);
    aq[0] = *(const bf16x8*)qp;
    aq[1] = *(const bf16x8*)(qp + 32);
  }
  f32x4 o[4] = {};
  float m_[4] = {-1e30f, -1e30f, -1e30f, -1e30f};
  float l_[4] = {0.f, 0.f, 0.f, 0.f};
  const int cmax = kNH + qt * 64;
  const int pr = t >> 2;   // staging row 0..63
  const int pc = t & 3;    // staging 16B chunk 0..3 (two chunks per thread)
  for (int c0 = 0; c0 <= cmax; c0 += 64) {
    const __bf16* kp = kv + ((size_t)(b * kW + c0 + pr) * 1024 + h * kA);
    bf16x8 kr0 = *(const bf16x8*)(kp + pc * 8);
    bf16x8 kr1 = *(const bf16x8*)(kp + pc * 8 + 32);
    bf16x8 vr0 = *(const bf16x8*)(kp + 512 + pc * 8);
    bf16x8 vr1 = *(const bf16x8*)(kp + 512 + pc * 8 + 32);
    __syncthreads();  // prior chunk's fragment reads complete
    *(bf16x8*)&Ks[pr * 72 + pc * 8] = kr0;
    *(bf16x8*)&Ks[pr * 72 + pc * 8 + 32] = kr1;
#pragma unroll
    for (int e = 0; e < 8; ++e) {
      Vt[(pc * 8 + e) * 72 + pr] = vr0[e];
      Vt[(pc * 8 + 32 + e) * 72 + pr] = vr1[e];
    }
    __syncthreads();
    // ---- S = Q @ K^T ----
    f32x4 s[4];
#pragma unroll
    for (int j = 0; j < 4; ++j) {
      f32x4 z = {};
      bf16x8 b0 = *(const bf16x8*)&Ks[(j * 16 + mr) * 72 + quad * 8];
      bf16x8 b1 = *(const bf16x8*)&Ks[(j * 16 + mr) * 72 + quad * 8 + 32];
      z = __builtin_amdgcn_mfma_f32_16x16x32_bf16(aq[0], b0, z, 0, 0, 0);
      z = __builtin_amdgcn_mfma_f32_16x16x32_bf16(aq[1], b1, z, 0, 0, 0);
      s[j] = z;
    }
    // ---- mask + scale + online softmax; row q = w*16 + quad*4 + r ----
    const int lim = cmax - c0;
#pragma unroll
    for (int r = 0; r < 4; ++r) {
      const int q = w * 16 + quad * 4 + r;
      float sv[4];
#pragma unroll
      for (int j = 0; j < 4; ++j)
        sv[j] = (j * 16 + mr < lim + q) ? s[j][r] * 0.125f : -1e30f;
      float mx = fmaxf(fmaxf(sv[0], sv[1]), fmaxf(sv[2], sv[3]));
      mx = fmaxf(mx, __shfl_xor(mx, 1));
      mx = fmaxf(mx, __shfl_xor(mx, 2));
      mx = fmaxf(mx, __shfl_xor(mx, 4));
      mx = fmaxf(mx, __shfl_xor(mx, 8));
      float mnew = fmaxf(m_[r], mx);
      float corr = __expf(m_[r] - mnew);
      float rs = 0.f;
#pragma unroll
      for (int j = 0; j < 4; ++j) {
        sv[j] = __expf(sv[j] - mnew);
        rs += sv[j];
      }
      rs += __shfl_xor(rs, 1);
      rs += __shfl_xor(rs, 2);
      rs += __shfl_xor(rs, 4);
      rs += __shfl_xor(rs, 8);
      l_[r] = l_[r] * corr + rs;
      m_[r] = mnew;
#pragma unroll
      for (int j = 0; j < 4; ++j) o[j][r] *= corr;
#pragma unroll
      for (int j = 0; j < 4; ++j) Ps[q * 72 + j * 16 + mr] = (__bf16)sv[j];
    }
    // ---- O += P @ V (wave-local P read; no barrier needed) ----
    bf16x8 ap0 = *(const bf16x8*)&Ps[(w * 16 + mr) * 72 + quad * 8];
    bf16x8 ap1 = *(const bf16x8*)&Ps[(w * 16 + mr) * 72 + quad * 8 + 32];
#pragma unroll
    for (int j = 0; j < 4; ++j) {
      bf16x8 b0 = *(const bf16x8*)&Vt[(j * 16 + mr) * 72 + quad * 8];
      bf16x8 b1 = *(const bf16x8*)&Vt[(j * 16 + mr) * 72 + quad * 8 + 32];
      o[j] = __builtin_amdgcn_mfma_f32_16x16x32_bf16(ap0, b0, o[j], 0, 0, 0);
      o[j] = __builtin_amdgcn_mfma_f32_16x16x32_bf16(ap1, b1, o[j], 0, 0, 0);
    }
  }
  // ---- epilogue ----
#pragma unroll
  for (int r = 0; r < 4; ++r) {
    float inv = 1.f / l_[r];
    int row = b * kNV + qt * 64 + w * 16 + quad * 4 + r;
#pragma unroll
    for (int j = 0; j < 4; ++j)
      out[(size_t)row * kHA + h * kA + j * 16 + mr] = o[j][r] * inv;
  }
}

// ---------------- att = LN(att + add); also emits bf16 copy ----------------
__global__ __launch_bounds__(256) void add_ln_kernel(
    float* __restrict__ att, const float* __restrict__ add,
    const float* __restrict__ g, const float* __restrict__ be,
    __bf16* __restrict__ attbf) {
  const int row = blockIdx.x;
  const int t = threadIdx.x;
  float* ar = att + (size_t)row * kHA;
  const float* dr = add + (size_t)row * kHA;
  float x0 = ar[t] + dr[t];
  float x1 = ar[t + 256] + dr[t + 256];
  float s = x0 + x1, sq = x0 * x0 + x1 * x1;
  for (int off = 32; off; off >>= 1) {
    s += __shfl_down(s, off);
    sq += __shfl_down(sq, off);
  }
  __shared__ float ssum[4], ssq[4], stats[2];
  if ((t & 63) == 0) { ssum[t >> 6] = s; ssq[t >> 6] = sq; }
  __syncthreads();
  if (t == 0) {
    float S = ssum[0] + ssum[1] + ssum[2] + ssum[3];
    float Q = ssq[0] + ssq[1] + ssq[2] + ssq[3];
    float mean = S * (1.f / kHA);
    float var = Q * (1.f / kHA) - mean * mean;
    stats[0] = mean;
    stats[1] = rsqrtf(var + 1e-5f);
  }
  __syncthreads();
  float mean = stats[0], inv = stats[1];
  float y0 = g[t] * (x0 - mean) * inv + be[t];
  float y1 = g[t + 256] * (x1 - mean) * inv + be[t + 256];
  ar[t] = y0;
  ar[t + 256] = y1;
  attbf[(size_t)row * kHA + t] = (__bf16)y0;
  attbf[(size_t)row * kHA + t + 256] = (__bf16)y1;
}

// ---------------- loss ----------------
__global__ __launch_bounds__(256) void loss_kernel(
    const float* __restrict__ logits, const float* __restrict__ pred_u,
    float* __restrict__ out) {
  const int b = blockIdx.x;
  const int t = threadIdx.x;
  float lp = 0.f;
  if (t >= 1) {
    const float* row = logits + (size_t)(b * kNV + t) * kR;
    float mx = -1e30f;
    for (int i = 0; i < kR; ++i) mx = fmaxf(mx, row[i]);
    float se = 0.f;
    for (int i = 0; i < kR; ++i) se += expf(row[i] - mx);
    float lse = mx + logf(se);
    float u = pred_u[b * kNV + t];
    int tgt = (int)floorf(u * (float)kR);
    tgt = max(0, min(kR - 1, tgt));
    lp = logf((float)kR) + row[tgt] - lse;
  }
  for (int off = 32; off; off >>= 1) lp += __shfl_down(lp, off);
  __shared__ float red[4];
  if ((t & 63) == 0) red[t >> 6] = lp;
  __syncthreads();
  if (t == 0) out[b] = -(red[0] + red[1] + red[2] + red[3]);
}

extern "C" void kernel_launch(void* const* d_in, const int* in_sizes, int n_in,
                              void* d_out, int out_size, void* d_ws, size_t ws_size,
                              hipStream_t stream) {
  const float* hist   = (const float*)d_in[0];
  const float* hist_u = (const float*)d_in[1];
  const float* pred   = (const float*)d_in[2];
  const float* pred_u = (const float*)d_in[3];
  const float* ds_w   = (const float*)d_in[4];
  const float* ds_b   = (const float*)d_in[5];
  const float* key_w  = (const float*)d_in[6];
  const float* key_b  = (const float*)d_in[7];
  const float* val_w  = (const float*)d_in[8];
  const float* val_b  = (const float*)d_in[9];
  const float* ln1_g  = (const float*)d_in[10];
  const float* ln1_b  = (const float*)d_in[11];
  const float* ln2_g  = (const float*)d_in[12];
  const float* ln2_b  = (const float*)d_in[13];
  const float* ff_w1  = (const float*)d_in[14];
  const float* ff_b1  = (const float*)d_in[15];
  const float* ff_w2  = (const float*)d_in[16];
  const float* ff_b2  = (const float*)d_in[17];
  const float* ff_w3  = (const float*)d_in[18];
  const float* ff_b3  = (const float*)d_in[19];
  const float* de_w   = (const float*)d_in[20];
  const float* de_b   = (const float*)d_in[21];
  float* out = (float*)d_out;

  char* ws = (char*)d_ws;
  size_t off = 0;
  auto alloc = [&](size_t bytes) { char* p = ws + off; off += bytes; return p; };
  __bf16* ki_bf   = (__bf16*)alloc((size_t)kB * kW * kKP * 2);
  __bf16* pred_bf = (__bf16*)alloc((size_t)kB * kNV * kD * 2);
  __bf16* kv_wt   = (__bf16*)alloc((size_t)kL * 1024 * kKP * 2);
  __bf16* ffw_t   = (__bf16*)alloc((size_t)12 * 512 * 512 * 2);
  __bf16* ds_wt   = (__bf16*)alloc((size_t)512 * 256 * 2);
  __bf16* de_wt   = (__bf16*)alloc((size_t)128 * 512 * 2);
  float*  kvb     = (float*)alloc((size_t)kL * 1024 * 4);
  __bf16* kvs     = (__bf16*)alloc((size_t)kB * kW * 1024 * 2);
  float*  att     = (float*)alloc((size_t)kB * kNV * kHA * 4);
  __bf16* att_bf  = (__bf16*)alloc((size_t)kB * kNV * kHA * 2);
  float*  tmp     = (float*)alloc((size_t)kB * kNV * kHA * 4);
  __bf16* ff1_bf  = (__bf16*)alloc((size_t)kB * kNV * kM * 2);
  __bf16* ff2_bf  = (__bf16*)alloc((size_t)kB * kNV * kM * 2);
  float*  logits  = (float*)alloc((size_t)kB * kNV * kR * 4);

  build_ki_bf_kernel<<<(kB * kW * kKP + 255) / 256, 256, 0, stream>>>(
      hist, hist_u, pred, pred_u, ki_bf);
  conv_pred_kernel<<<(kB * kNV * kD + 255) / 256, 256, 0, stream>>>(pred, pred_bf);
  conv_kvw_kernel<<<(kL * 1024 * kKP + 255) / 256, 256, 0, stream>>>(key_w, val_w,
                                                                     kv_wt);
  conv_ffw_kernel<<<(12 * 512 * 512 + 255) / 256, 256, 0, stream>>>(ff_w1, ff_w2,
                                                                    ff_w3, ffw_t);
  conv_misc_kernel<<<(200704 + 255) / 256, 256, 0, stream>>>(
      ds_w, de_w, key_b, val_b, ds_wt, de_wt, kvb);

  // att = pred @ ds_w + ds_b (fp32 + bf16 out)
  gemm_mfma_kernel<2, false><<<dim3(kHA / 128, kB * kNV / 128), 256, 0, stream>>>(
      pred_bf, ds_wt, ds_b, att, att_bf, kB * kNV, kHA, kD);

  for (int l = 0; l < kL; ++l) {
    gemm_mfma_kernel<1, false><<<dim3(1024 / 128, kB * kW / 128), 256, 0,
                                 stream>>>(ki_bf, kv_wt + (size_t)l * 1024 * kKP,
                                           kvb + l * 1024, kvs, nullptr, kB * kW,
                                           1024, kKP);
    attn_mfma_kernel<<<dim3(kNV / 64, kH, kB), 256, 0, stream>>>(att_bf, kvs, tmp);
    add_ln_kernel<<<kB * kNV, 256, 0, stream>>>(att, tmp, ln1_g + l * kHA,
                                                ln1_b + l * kHA, att_bf);
    gemm_mfma_kernel<1, true><<<dim3(kM / 128, kB * kNV / 128), 256, 0, stream>>>(
        att_bf, ffw_t + (size_t)(l * 3) * 262144, ff_b1 + l * kM, ff1_bf, nullptr,
        kB * kNV, kM, kHA);
    gemm_mfma_kernel<1, true><<<dim3(kM / 128, kB * kNV / 128), 256, 0, stream>>>(
        ff1_bf, ffw_t + (size_t)(l * 3 + 1) * 262144, ff_b2 + l * kM, ff2_bf,
        nullptr, kB * kNV, kM, kM);
    gemm_mfma_kernel<0, false><<<dim3(kHA / 128, kB * kNV / 128), 256, 0,
                                 stream>>>(ff2_bf,
                                           ffw_t + (size_t)(l * 3 + 2) * 262144,
                                           ff_b3 + l * kHA, tmp, nullptr, kB * kNV,
                                           kHA, kM);
    add_ln_kernel<<<kB * kNV, 256, 0, stream>>>(att, tmp, ln2_g + l * kHA,
                                                ln2_b + l * kHA, att_bf);
  }
  gemm_mfma_kernel<0, false><<<dim3(kR / 128, kB * kNV / 128), 256, 0, stream>>>(
      att_bf, de_wt, de_b, logits, nullptr, kB * kNV, kR, kHA);
  loss_kernel<<<kB, 256, 0, stream>>>(logits, pred_u, out);
}

// Round 5
// 535.987 us; speedup vs baseline: 8.8463x; 1.0777x over previous
//
#include <hip/hip_runtime.h>

// Problem constants (AttentionalCopula)
constexpr int kB = 16, kD = 256, kNH = 512, kNV = 256, kW = 768;
constexpr int kL = 4, kH = 8, kA = 64, kHA = 512, kM = 512, kR = 128;
constexpr int kKP = 288;  // K=257 zero-padded to multiple of 32

typedef __bf16 bf16x8 __attribute__((ext_vector_type(8)));
typedef __bf16 bf16x4 __attribute__((ext_vector_type(4)));
typedef float f32x4 __attribute__((ext_vector_type(4)));

__device__ inline void load_lds16(const __bf16* g, __bf16* l) {
  __builtin_amdgcn_global_load_lds(
      (const __attribute__((address_space(1))) void*)g,
      (__attribute__((address_space(3))) void*)l, 16, 0, 0);
}

// ---------------- prep kernels ----------------
__global__ void build_ki_bf_kernel(const float* __restrict__ hist,
                                   const float* __restrict__ hist_u,
                                   const float* __restrict__ pred,
                                   const float* __restrict__ pred_u,
                                   __bf16* __restrict__ ki) {
  int i = blockIdx.x * 256 + threadIdx.x;
  const int total = kB * kW * kKP;
  if (i >= total) return;
  int d = i % kKP;
  int bw = i / kKP;
  int w = bw % kW;
  int b = bw / kW;
  float v = 0.f;
  if (d < 257) {
    if (w < kNH)
      v = (d < kD) ? hist[((size_t)b * kNH + w) * kD + d] : hist_u[b * kNH + w];
    else {
      int p = w - kNH;
      v = (d < kD) ? pred[((size_t)b * kNV + p) * kD + d] : pred_u[b * kNV + p];
    }
  }
  ki[i] = (__bf16)v;
}

// kv weights -> [4096 cols][288] bf16 transposed; col = l*1024 + kv*512 + h*64 + a
__global__ void conv_kvw_kernel(const float* __restrict__ kw,
                                const float* __restrict__ vw,
                                __bf16* __restrict__ kvwt) {
  int i = blockIdx.x * 256 + threadIdx.x;
  const int total = kL * 1024 * kKP;
  if (i >= total) return;
  int d = i % kKP;
  int c = (i / kKP) & 1023;
  int l = i / (kKP * 1024);
  float v = 0.f;
  if (d < 257) {
    int kvv = c >> 9, h = (c >> 6) & 7, a = c & 63;
    size_t src = (((size_t)l * kH + h) * 257 + d) * kA + a;
    v = kvv ? vw[src] : kw[src];
  }
  kvwt[i] = (__bf16)v;
}

__global__ void conv_ffw_kernel(const float* __restrict__ w1,
                                const float* __restrict__ w2,
                                const float* __restrict__ w3,
                                __bf16* __restrict__ out) {
  int i = blockIdx.x * 256 + threadIdx.x;
  const int total = 12 * 512 * 512;
  if (i >= total) return;
  int k = i & 511;
  int n = (i >> 9) & 511;
  int mat = i >> 18;
  int l = mat / 3, which = mat % 3;
  const float* src = which == 0 ? w1 : which == 1 ? w2 : w3;
  out[i] = (__bf16)src[((size_t)l * 512 + k) * 512 + n];
}

__global__ void conv_misc_kernel(const float* __restrict__ ds_w,
                                 const float* __restrict__ de_w,
                                 const float* __restrict__ key_b,
                                 const float* __restrict__ val_b,
                                 __bf16* __restrict__ ds_wt,
                                 __bf16* __restrict__ de_wt,
                                 float* __restrict__ kvb) {
  int i = blockIdx.x * 256 + threadIdx.x;
  if (i < 131072) {
    int n = i >> 8, k = i & 255;
    ds_wt[i] = (__bf16)ds_w[k * 512 + n];
  } else if (i < 196608) {
    int j = i - 131072;
    int n = j >> 9, k = j & 511;
    de_wt[j] = (__bf16)de_w[k * 128 + n];
  } else if (i < 200704) {
    int j = i - 196608;
    int l = j >> 10, c = j & 1023;
    kvb[j] = (c < 512) ? key_b[l * 512 + c] : val_b[l * 512 + (c - 512)];
  }
}

// ---------------- bf16 MFMA GEMM ----------------
// C[M,N] = A[M,K]@B[K,N] + bias; Bt = B transposed [N][K]. BM=128, BN template
// (64 or 128). 4 waves 2x2. OMODE: 0=f32, 1=bf16, 2=both. KIMAP: A rows remap
// r -> (r>>8)*768 + 512 + (r&255) (pred rows inside ki; affine per 128-block).
template <int BN, int OMODE, bool RELU, bool KIMAP>
__global__ __launch_bounds__(256) void gemm_mfma_kernel(
    const __bf16* __restrict__ A, const __bf16* __restrict__ Bt,
    const float* __restrict__ bias, void* __restrict__ Cout,
    __bf16* __restrict__ Cout2, int M, int N, int K, int lda) {
  constexpr int JN = BN / 32;      // j-tiles per wave (n-dir)
  constexpr int BROWS = BN / 4;    // B rows staged per wave
  __shared__ __bf16 As[128 * 32];
  __shared__ __bf16 Bs[BN * 32];
  const int t = threadIdx.x;
  const int wid = t >> 6;
  const int lane = t & 63;
  const int bm = blockIdx.y * 128;
  const int bn = blockIdx.x * BN;
  const int wm = (wid >> 1) * 64;
  const int wn = (wid & 1) * (BN / 2);
  const int sr = lane >> 2, sc = lane & 3;
  const int abase = KIMAP ? ((bm >> 8) * 768 + 512 + (bm & 255)) : bm;
  const __bf16* Ag = A + (size_t)(abase + wid * 32 + sr) * lda + sc * 8;
  const __bf16* Bg = Bt + (size_t)(bn + wid * BROWS + sr) * K + sc * 8;
  __bf16* AsW = As + (wid * 32) * 32;
  __bf16* BsW = Bs + (wid * BROWS) * 32;

  f32x4 acc[4][JN] = {};
  const int q = lane >> 4, mr = lane & 15;
  for (int k0 = 0; k0 < K; k0 += 32) {
    if (k0) __syncthreads();
    load_lds16(Ag + k0, AsW);
    load_lds16(Ag + (size_t)16 * lda + k0, AsW + 16 * 32);
    load_lds16(Bg + k0, BsW);
    if (BN == 128) load_lds16(Bg + (size_t)16 * K + k0, BsW + 16 * 32);
    __syncthreads();
    bf16x8 af[4], bfr[JN];
#pragma unroll
    for (int i = 0; i < 4; ++i)
      af[i] = *(const bf16x8*)(As + (wm + i * 16 + mr) * 32 + q * 8);
#pragma unroll
    for (int j = 0; j < JN; ++j)
      bfr[j] = *(const bf16x8*)(Bs + (wn + j * 16 + mr) * 32 + q * 8);
#pragma unroll
    for (int i = 0; i < 4; ++i)
#pragma unroll
      for (int j = 0; j < JN; ++j)
        acc[i][j] = __builtin_amdgcn_mfma_f32_16x16x32_bf16(af[i], bfr[j],
                                                            acc[i][j], 0, 0, 0);
  }
#pragma unroll
  for (int j = 0; j < JN; ++j) {
    int col = bn + wn + j * 16 + mr;
    float bs = bias[col];
#pragma unroll
    for (int i = 0; i < 4; ++i) {
      int row0 = bm + wm + i * 16 + q * 4;
#pragma unroll
      for (int r = 0; r < 4; ++r) {
        float v = acc[i][j][r] + bs;
        if (RELU) v = fmaxf(v, 0.f);
        size_t idx = (size_t)(row0 + r) * N + col;
        if (OMODE == 0) {
          ((float*)Cout)[idx] = v;
        } else if (OMODE == 1) {
          ((__bf16*)Cout)[idx] = (__bf16)v;
        } else {
          ((float*)Cout)[idx] = v;
          Cout2[idx] = (__bf16)v;
        }
      }
    }
  }
}

// ---------------- MFMA flash attention (S^T variant) ----------------
// Block = 4 waves per (b, h, 64-q tile). S^T = K·Q^T (swap MFMA operands:
// K rows as A from LDS, Q regs as B) -> softmax state is scalar per lane
// (col = q = mr); reductions via shfl_xor 16/32 only. P written as b64 packs,
// read back wave-locally as A-frag for O = P·V (V staged transposed).
__global__ __launch_bounds__(256) void attn_mfma_kernel(
    const __bf16* __restrict__ attbf, const __bf16* __restrict__ kv,
    float* __restrict__ out) {
  const int b = blockIdx.z, h = blockIdx.y, qt = blockIdx.x;
  __shared__ __bf16 Ks[64 * 72];
  __shared__ __bf16 Vt[64 * 72];
  __shared__ __bf16 Ps[64 * 72];
  const int t = threadIdx.x;
  const int w = t >> 6, lane = t & 63;
  const int quad = lane >> 4, mr = lane & 15;
  bf16x8 aq[2];
  {
    const __bf16* qp = attbf + ((size_t)(b * kNV + qt * 64 + w * 16 + mr) * kHA +
                                h * kA + quad * 8);
    aq[0] = *(const bf16x8*)qp;
    aq[1] = *(const bf16x8*)(qp + 32);
  }
  f32x4 o[4] = {};
  float m_ = -1e30f, l_ = 0.f;  // stats for q_local = mr (wave-relative)
  const int cmax = kNH + qt * 64;
  const int pr = t >> 2, pc = t & 3;
  for (int c0 = 0; c0 <= cmax; c0 += 64) {
    const __bf16* kp = kv + ((size_t)(b * kW + c0 + pr) * 4096 + h * kA);
    bf16x8 kr0 = *(const bf16x8*)(kp + pc * 8);
    bf16x8 kr1 = *(const bf16x8*)(kp + pc * 8 + 32);
    bf16x8 vr0 = *(const bf16x8*)(kp + 512 + pc * 8);
    bf16x8 vr1 = *(const bf16x8*)(kp + 512 + pc * 8 + 32);
    __syncthreads();
    *(bf16x8*)&Ks[pr * 72 + pc * 8] = kr0;
    *(bf16x8*)&Ks[pr * 72 + pc * 8 + 32] = kr1;
#pragma unroll
    for (int e = 0; e < 8; ++e) {
      Vt[(pc * 8 + e) * 72 + pr] = vr0[e];
      Vt[(pc * 8 + 32 + e) * 72 + pr] = vr1[e];
    }
    __syncthreads();
    // ---- S^T = K·Q^T : s[j][r] = S[p = j*16+quad*4+r][q = mr] ----
    f32x4 s[4];
#pragma unroll
    for (int j = 0; j < 4; ++j) {
      bf16x8 ak0 = *(const bf16x8*)&Ks[(j * 16 + mr) * 72 + quad * 8];
      bf16x8 ak1 = *(const bf16x8*)&Ks[(j * 16 + mr) * 72 + quad * 8 + 32];
      f32x4 z = {};
      z = __builtin_amdgcn_mfma_f32_16x16x32_bf16(ak0, aq[0], z, 0, 0, 0);
      z = __builtin_amdgcn_mfma_f32_16x16x32_bf16(ak1, aq[1], z, 0, 0, 0);
      s[j] = z;
    }
    // ---- mask + scale + online softmax (per-lane scalar state) ----
    const int lim = cmax - c0;  // valid iff p < lim + q
    float sv[16], mx = -1e30f;
#pragma unroll
    for (int j = 0; j < 4; ++j)
#pragma unroll
      for (int r = 0; r < 4; ++r) {
        int p = j * 16 + quad * 4 + r;
        float x = (p < lim + mr) ? s[j][r] * 0.125f : -1e30f;
        sv[j * 4 + r] = x;
        mx = fmaxf(mx, x);
      }
    mx = fmaxf(mx, __shfl_xor(mx, 16));
    mx = fmaxf(mx, __shfl_xor(mx, 32));
    float mnew = fmaxf(m_, mx);
    float corr = __expf(m_ - mnew);
    float rs = 0.f;
#pragma unroll
    for (int i = 0; i < 16; ++i) {
      sv[i] = __expf(sv[i] - mnew);
      rs += sv[i];
    }
    rs += __shfl_xor(rs, 16);
    rs += __shfl_xor(rs, 32);
    l_ = l_ * corr + rs;
    m_ = mnew;
    // ---- store P (rows q = w*16+mr, wave-local) as 4x bf16x4 ----
#pragma unroll
    for (int j = 0; j < 4; ++j) {
      bf16x4 pk = {(__bf16)sv[j * 4 + 0], (__bf16)sv[j * 4 + 1],
                   (__bf16)sv[j * 4 + 2], (__bf16)sv[j * 4 + 3]};
      *(bf16x4*)&Ps[(w * 16 + mr) * 72 + j * 16 + quad * 4] = pk;
    }
    // ---- rescale O (rows q = quad*4+r): remap corr via shfl ----
#pragma unroll
    for (int r = 0; r < 4; ++r) {
      float cr = __shfl(corr, quad * 4 + r);
#pragma unroll
      for (int j = 0; j < 4; ++j) o[j][r] *= cr;
    }
    // ---- O += P·V ----
    bf16x8 ap0 = *(const bf16x8*)&Ps[(w * 16 + mr) * 72 + quad * 8];
    bf16x8 ap1 = *(const bf16x8*)&Ps[(w * 16 + mr) * 72 + quad * 8 + 32];
#pragma unroll
    for (int j = 0; j < 4; ++j) {
      bf16x8 b0 = *(const bf16x8*)&Vt[(j * 16 + mr) * 72 + quad * 8];
      bf16x8 b1 = *(const bf16x8*)&Vt[(j * 16 + mr) * 72 + quad * 8 + 32];
      o[j] = __builtin_amdgcn_mfma_f32_16x16x32_bf16(ap0, b0, o[j], 0, 0, 0);
      o[j] = __builtin_amdgcn_mfma_f32_16x16x32_bf16(ap1, b1, o[j], 0, 0, 0);
    }
  }
  // ---- epilogue ----
  float invl = 1.f / l_;
#pragma unroll
  for (int r = 0; r < 4; ++r) {
    float ir = __shfl(invl, quad * 4 + r);
    int row = b * kNV + qt * 64 + w * 16 + quad * 4 + r;
#pragma unroll
    for (int j = 0; j < 4; ++j)
      out[(size_t)row * kHA + h * kA + j * 16 + mr] = o[j][r] * ir;
  }
}

// ---------------- att = LN(att + add); also emits bf16 copy ----------------
__global__ __launch_bounds__(256) void add_ln_kernel(
    float* __restrict__ att, const float* __restrict__ add,
    const float* __restrict__ g, const float* __restrict__ be,
    __bf16* __restrict__ attbf) {
  const int row = blockIdx.x;
  const int t = threadIdx.x;
  float* ar = att + (size_t)row * kHA;
  const float* dr = add + (size_t)row * kHA;
  float x0 = ar[t] + dr[t];
  float x1 = ar[t + 256] + dr[t + 256];
  float s = x0 + x1, sq = x0 * x0 + x1 * x1;
  for (int off = 32; off; off >>= 1) {
    s += __shfl_down(s, off);
    sq += __shfl_down(sq, off);
  }
  __shared__ float ssum[4], ssq[4], stats[2];
  if ((t & 63) == 0) { ssum[t >> 6] = s; ssq[t >> 6] = sq; }
  __syncthreads();
  if (t == 0) {
    float S = ssum[0] + ssum[1] + ssum[2] + ssum[3];
    float Q = ssq[0] + ssq[1] + ssq[2] + ssq[3];
    float mean = S * (1.f / kHA);
    float var = Q * (1.f / kHA) - mean * mean;
    stats[0] = mean;
    stats[1] = rsqrtf(var + 1e-5f);
  }
  __syncthreads();
  float mean = stats[0], inv = stats[1];
  float y0 = g[t] * (x0 - mean) * inv + be[t];
  float y1 = g[t + 256] * (x1 - mean) * inv + be[t + 256];
  ar[t] = y0;
  ar[t + 256] = y1;
  attbf[(size_t)row * kHA + t] = (__bf16)y0;
  attbf[(size_t)row * kHA + t + 256] = (__bf16)y1;
}

// ---------------- fused de-projection + loss partials ----------------
// 64 blocks x 64 rows. logits = attbf[row]·de_wt + de_b via MFMA (B from
// global, L1/L2-cached). Per-row lse + target pick; per-block partial sum.
__global__ __launch_bounds__(256) void de_loss_kernel(
    const __bf16* __restrict__ attbf, const __bf16* __restrict__ de_wt,
    const float* __restrict__ de_b, const float* __restrict__ pred_u,
    float* __restrict__ parts) {
  const int blk = blockIdx.x;
  const int t = threadIdx.x;
  const int w = t >> 6, lane = t & 63, quad = lane >> 4, mr = lane & 15;
  const int row0 = blk * 64 + w * 16;
  f32x4 acc[8] = {};
  const __bf16* Ap = attbf + (size_t)(row0 + mr) * kHA + quad * 8;
#pragma unroll 4
  for (int k0 = 0; k0 < 512; k0 += 32) {
    bf16x8 a = *(const bf16x8*)(Ap + k0);
#pragma unroll
    for (int j = 0; j < 8; ++j) {
      bf16x8 bb =
          *(const bf16x8*)(de_wt + (size_t)(j * 16 + mr) * 512 + k0 + quad * 8);
      acc[j] = __builtin_amdgcn_mfma_f32_16x16x32_bf16(a, bb, acc[j], 0, 0, 0);
    }
  }
  float dbv[8];
#pragma unroll
  for (int j = 0; j < 8; ++j) dbv[j] = de_b[j * 16 + mr];
  float lpacc = 0.f;
#pragma unroll
  for (int r = 0; r < 4; ++r) {
    int row = row0 + quad * 4 + r;
    int v = row & 255, bidx = row >> 8;
    float lg[8], mx = -1e30f;
#pragma unroll
    for (int j = 0; j < 8; ++j) {
      lg[j] = acc[j][r] + dbv[j];
      mx = fmaxf(mx, lg[j]);
    }
    mx = fmaxf(mx, __shfl_xor(mx, 1));
    mx = fmaxf(mx, __shfl_xor(mx, 2));
    mx = fmaxf(mx, __shfl_xor(mx, 4));
    mx = fmaxf(mx, __shfl_xor(mx, 8));
    float se = 0.f;
#pragma unroll
    for (int j = 0; j < 8; ++j) se += __expf(lg[j] - mx);
    se += __shfl_xor(se, 1);
    se += __shfl_xor(se, 2);
    se += __shfl_xor(se, 4);
    se += __shfl_xor(se, 8);
    float lse = mx + __logf(se);
    float u = pred_u[bidx * 256 + v];
    int tgt = (int)floorf(u * 128.f);
    tgt = max(0, min(127, tgt));
    float cand = (mr == (tgt & 15)) ? lg[tgt >> 4] : 0.f;
    cand += __shfl_xor(cand, 1);
    cand += __shfl_xor(cand, 2);
    cand += __shfl_xor(cand, 4);
    cand += __shfl_xor(cand, 8);
    float lp = (v >= 1) ? (4.8520302639196171f + cand - lse) : 0.f;  // ln(128)
    lpacc += lp;
  }
  lpacc += __shfl_xor(lpacc, 16);
  lpacc += __shfl_xor(lpacc, 32);
  __shared__ float red[4];
  if (lane == 0) red[w] = lpacc;
  __syncthreads();
  if (t == 0) parts[blk] = red[0] + red[1] + red[2] + red[3];
}

__global__ void loss_final_kernel(const float* __restrict__ parts,
                                  float* __restrict__ out) {
  int b = threadIdx.x;
  if (b < kB)
    out[b] = -(parts[b * 4] + parts[b * 4 + 1] + parts[b * 4 + 2] +
               parts[b * 4 + 3]);
}

extern "C" void kernel_launch(void* const* d_in, const int* in_sizes, int n_in,
                              void* d_out, int out_size, void* d_ws, size_t ws_size,
                              hipStream_t stream) {
  const float* hist   = (const float*)d_in[0];
  const float* hist_u = (const float*)d_in[1];
  const float* pred   = (const float*)d_in[2];
  const float* pred_u = (const float*)d_in[3];
  const float* ds_w   = (const float*)d_in[4];
  const float* ds_b   = (const float*)d_in[5];
  const float* key_w  = (const float*)d_in[6];
  const float* key_b  = (const float*)d_in[7];
  const float* val_w  = (const float*)d_in[8];
  const float* val_b  = (const float*)d_in[9];
  const float* ln1_g  = (const float*)d_in[10];
  const float* ln1_b  = (const float*)d_in[11];
  const float* ln2_g  = (const float*)d_in[12];
  const float* ln2_b  = (const float*)d_in[13];
  const float* ff_w1  = (const float*)d_in[14];
  const float* ff_b1  = (const float*)d_in[15];
  const float* ff_w2  = (const float*)d_in[16];
  const float* ff_b2  = (const float*)d_in[17];
  const float* ff_w3  = (const float*)d_in[18];
  const float* ff_b3  = (const float*)d_in[19];
  const float* de_w   = (const float*)d_in[20];
  const float* de_b   = (const float*)d_in[21];
  float* out = (float*)d_out;

  char* ws = (char*)d_ws;
  size_t off = 0;
  auto alloc = [&](size_t bytes) { char* p = ws + off; off += bytes; return p; };
  __bf16* ki_bf  = (__bf16*)alloc((size_t)kB * kW * kKP * 2);       // 7.1 MB
  __bf16* kv_wt  = (__bf16*)alloc((size_t)kL * 1024 * kKP * 2);     // 2.4 MB
  __bf16* ffw_t  = (__bf16*)alloc((size_t)12 * 512 * 512 * 2);      // 6.3 MB
  __bf16* ds_wt  = (__bf16*)alloc((size_t)512 * 256 * 2);
  __bf16* de_wt  = (__bf16*)alloc((size_t)128 * 512 * 2);
  float*  kvb    = (float*)alloc((size_t)kL * 1024 * 4);
  __bf16* kvs    = (__bf16*)alloc((size_t)kB * kW * 4096 * 2);      // 100.7 MB
  float*  att    = (float*)alloc((size_t)kB * kNV * kHA * 4);       // 8.4 MB
  __bf16* att_bf = (__bf16*)alloc((size_t)kB * kNV * kHA * 2);
  float*  tmp    = (float*)alloc((size_t)kB * kNV * kHA * 4);
  __bf16* ff1_bf = (__bf16*)alloc((size_t)kB * kNV * kM * 2);
  __bf16* ff2_bf = (__bf16*)alloc((size_t)kB * kNV * kM * 2);
  float*  parts  = (float*)alloc(64 * 4);

  build_ki_bf_kernel<<<(kB * kW * kKP + 255) / 256, 256, 0, stream>>>(
      hist, hist_u, pred, pred_u, ki_bf);
  conv_kvw_kernel<<<(kL * 1024 * kKP + 255) / 256, 256, 0, stream>>>(key_w, val_w,
                                                                     kv_wt);
  conv_ffw_kernel<<<(12 * 512 * 512 + 255) / 256, 256, 0, stream>>>(ff_w1, ff_w2,
                                                                    ff_w3, ffw_t);
  conv_misc_kernel<<<(200704 + 255) / 256, 256, 0, stream>>>(
      ds_w, de_w, key_b, val_b, ds_wt, de_wt, kvb);

  // att = pred @ ds_w + ds_b (fp32 + bf16); A = pred rows inside ki (KIMAP)
  gemm_mfma_kernel<64, 2, false, true>
      <<<dim3(kHA / 64, kB * kNV / 128), 256, 0, stream>>>(
          ki_bf, ds_wt, ds_b, att, att_bf, kB * kNV, kHA, kD, kKP);

  // keys||vals for ALL layers: [12288, 4096] bf16
  gemm_mfma_kernel<128, 1, false, false>
      <<<dim3(4096 / 128, kB * kW / 128), 256, 0, stream>>>(
          ki_bf, kv_wt, kvb, kvs, nullptr, kB * kW, 4096, kKP, kKP);

  for (int l = 0; l < kL; ++l) {
    attn_mfma_kernel<<<dim3(kNV / 64, kH, kB), 256, 0, stream>>>(
        att_bf, kvs + (size_t)l * 1024, tmp);
    add_ln_kernel<<<kB * kNV, 256, 0, stream>>>(att, tmp, ln1_g + l * kHA,
                                                ln1_b + l * kHA, att_bf);
    gemm_mfma_kernel<64, 1, true, false>
        <<<dim3(kM / 64, kB * kNV / 128), 256, 0, stream>>>(
            att_bf, ffw_t + (size_t)(l * 3) * 262144, ff_b1 + l * kM, ff1_bf,
            nullptr, kB * kNV, kM, kHA, kHA);
    gemm_mfma_kernel<64, 1, true, false>
        <<<dim3(kM / 64, kB * kNV / 128), 256, 0, stream>>>(
            ff1_bf, ffw_t + (size_t)(l * 3 + 1) * 262144, ff_b2 + l * kM, ff2_bf,
            nullptr, kB * kNV, kM, kM, kM);
    gemm_mfma_kernel<64, 0, false, false>
        <<<dim3(kHA / 64, kB * kNV / 128), 256, 0, stream>>>(
            ff2_bf, ffw_t + (size_t)(l * 3 + 2) * 262144, ff_b3 + l * kHA, tmp,
            nullptr, kB * kNV, kHA, kM, kM);
    add_ln_kernel<<<kB * kNV, 256, 0, stream>>>(att, tmp, ln2_g + l * kHA,
                                                ln2_b + l * kHA, att_bf);
  }
  de_loss_kernel<<<64, 256, 0, stream>>>(att_bf, de_wt, de_b, pred_u, parts);
  loss_final_kernel<<<1, 64, 0, stream>>>(parts, out);
}

// Round 6
// 520.334 us; speedup vs baseline: 9.1124x; 1.0301x over previous
//
#include <hip/hip_runtime.h>

// Problem constants (AttentionalCopula)
constexpr int kB = 16, kD = 256, kNH = 512, kNV = 256, kW = 768;
constexpr int kL = 4, kH = 8, kA = 64, kHA = 512, kM = 512, kR = 128;
constexpr int kKP = 288;  // K=257 zero-padded to multiple of 32

typedef __bf16 bf16x8 __attribute__((ext_vector_type(8)));
typedef __bf16 bf16x4 __attribute__((ext_vector_type(4)));
typedef float f32x4 __attribute__((ext_vector_type(4)));

__device__ inline void load_lds16(const __bf16* g, __bf16* l) {
  __builtin_amdgcn_global_load_lds(
      (const __attribute__((address_space(1))) void*)g,
      (__attribute__((address_space(3))) void*)l, 16, 0, 0);
}

// ---------------- prep kernels ----------------
__global__ void build_ki_bf_kernel(const float* __restrict__ hist,
                                   const float* __restrict__ hist_u,
                                   const float* __restrict__ pred,
                                   const float* __restrict__ pred_u,
                                   __bf16* __restrict__ ki) {
  int i = blockIdx.x * 256 + threadIdx.x;
  const int total = kB * kW * kKP;
  if (i >= total) return;
  int d = i % kKP;
  int bw = i / kKP;
  int w = bw % kW;
  int b = bw / kW;
  float v = 0.f;
  if (d < 257) {
    if (w < kNH)
      v = (d < kD) ? hist[((size_t)b * kNH + w) * kD + d] : hist_u[b * kNH + w];
    else {
      int p = w - kNH;
      v = (d < kD) ? pred[((size_t)b * kNV + p) * kD + d] : pred_u[b * kNV + p];
    }
  }
  ki[i] = (__bf16)v;
}

// kv weights -> [4096 cols][288] bf16 transposed.
// cols 0..2047: keys (l*512 + h*64 + a); cols 2048..4095: values.
__global__ void conv_kvw_kernel(const float* __restrict__ kw,
                                const float* __restrict__ vw,
                                __bf16* __restrict__ kvwt) {
  int i = blockIdx.x * 256 + threadIdx.x;
  const int total = 4096 * kKP;
  if (i >= total) return;
  int d = i % kKP;
  int c = i / kKP;
  float v = 0.f;
  if (d < 257) {
    bool isv = c >= 2048;
    int cc = isv ? c - 2048 : c;
    int l = cc >> 9, rest = cc & 511;
    int h = rest >> 6, a = rest & 63;
    size_t src = (((size_t)l * kH + h) * 257 + d) * kA + a;
    v = isv ? vw[src] : kw[src];
  }
  kvwt[i] = (__bf16)v;
}

__global__ void conv_ffw_kernel(const float* __restrict__ w1,
                                const float* __restrict__ w2,
                                const float* __restrict__ w3,
                                __bf16* __restrict__ out) {
  int i = blockIdx.x * 256 + threadIdx.x;
  const int total = 12 * 512 * 512;
  if (i >= total) return;
  int k = i & 511;
  int n = (i >> 9) & 511;
  int mat = i >> 18;
  int l = mat / 3, which = mat % 3;
  const float* src = which == 0 ? w1 : which == 1 ? w2 : w3;
  out[i] = (__bf16)src[((size_t)l * 512 + k) * 512 + n];
}

__global__ void conv_misc_kernel(const float* __restrict__ ds_w,
                                 const float* __restrict__ de_w,
                                 const float* __restrict__ key_b,
                                 const float* __restrict__ val_b,
                                 __bf16* __restrict__ ds_wt,
                                 __bf16* __restrict__ de_wt,
                                 float* __restrict__ kvb) {
  int i = blockIdx.x * 256 + threadIdx.x;
  if (i < 131072) {
    int n = i >> 8, k = i & 255;
    ds_wt[i] = (__bf16)ds_w[k * 512 + n];
  } else if (i < 196608) {
    int j = i - 131072;
    int n = j >> 9, k = j & 511;
    de_wt[j] = (__bf16)de_w[k * 128 + n];
  } else if (i < 200704) {
    int c = i - 196608;  // 0..4095
    bool isv = c >= 2048;
    int cc = isv ? c - 2048 : c;
    int l = cc >> 9, rest = cc & 511;
    kvb[c] = isv ? val_b[l * 512 + rest] : key_b[l * 512 + rest];
  }
}

// ---------------- bf16 MFMA GEMM ----------------
// C[M,N] = A[M,K]@B[K,N] + bias; Bt = B transposed [N][K]. BM=128, BN 64/128.
// XOR-swizzled LDS (chunk ^= (row>>1)&3) for conflict-free b128 reads.
// KIMAP: A rows remap r -> (r>>8)*768 + 512 + (r&255). VEPI: blocks with
// bn>=2048 write C transposed into vT[l][b][col512][768] via LDS transpose.
template <int BN, int OMODE, bool RELU, bool KIMAP, bool VEPI>
__global__ __launch_bounds__(256) void gemm_mfma_kernel(
    const __bf16* __restrict__ A, const __bf16* __restrict__ Bt,
    const float* __restrict__ bias, void* __restrict__ Cout,
    __bf16* __restrict__ Cout2, __bf16* __restrict__ vT,
    int M, int N, int K, int lda, int ldc) {
  constexpr int JN = BN / 32;
  constexpr int BROWS = BN / 4;
  constexpr int kAB = 128 * 32 + BN * 32;
  constexpr int kCt = VEPI ? 64 * 136 : 0;
  constexpr int kSmem = kAB > kCt ? kAB : kCt;
  __shared__ __bf16 smem[kSmem];
  __bf16* As = smem;
  __bf16* Bs = smem + 128 * 32;
  const int t = threadIdx.x;
  const int wid = t >> 6;
  const int lane = t & 63;
  const int bm = blockIdx.y * 128;
  const int bn = blockIdx.x * BN;
  const int wm = (wid >> 1) * 64;
  const int wn = (wid & 1) * (BN / 2);
  const int sr = lane >> 2, sc = lane & 3;
  const int skey = (sr >> 1) & 3;
  const int abase = KIMAP ? ((bm >> 8) * 768 + 512 + (bm & 255)) : bm;
  const __bf16* Ag = A + (size_t)(abase + wid * 32 + sr) * lda + (sc ^ skey) * 8;
  const __bf16* Bg = Bt + (size_t)(bn + wid * BROWS + sr) * K + (sc ^ skey) * 8;
  __bf16* AsW = As + (wid * 32) * 32;
  __bf16* BsW = Bs + (wid * BROWS) * 32;

  f32x4 acc[4][JN] = {};
  const int q = lane >> 4, mr = lane & 15;
  const int rkey = (mr >> 1) & 3;
  for (int k0 = 0; k0 < K; k0 += 32) {
    if (k0) __syncthreads();
    load_lds16(Ag + k0, AsW);
    load_lds16(Ag + (size_t)16 * lda + k0, AsW + 16 * 32);
    load_lds16(Bg + k0, BsW);
    if (BN == 128) load_lds16(Bg + (size_t)16 * K + k0, BsW + 16 * 32);
    __syncthreads();
    bf16x8 af[4], bfr[JN];
#pragma unroll
    for (int i = 0; i < 4; ++i)
      af[i] = *(const bf16x8*)(As + (wm + i * 16 + mr) * 32 + (q ^ rkey) * 8);
#pragma unroll
    for (int j = 0; j < JN; ++j)
      bfr[j] = *(const bf16x8*)(Bs + (wn + j * 16 + mr) * 32 + (q ^ rkey) * 8);
#pragma unroll
    for (int i = 0; i < 4; ++i)
#pragma unroll
      for (int j = 0; j < JN; ++j)
        acc[i][j] = __builtin_amdgcn_mfma_f32_16x16x32_bf16(af[i], bfr[j],
                                                            acc[i][j], 0, 0, 0);
  }
  if (!VEPI || bn < 2048) {
#pragma unroll
    for (int j = 0; j < JN; ++j) {
      int col = bn + wn + j * 16 + mr;
      float bs = bias[col];
#pragma unroll
      for (int i = 0; i < 4; ++i) {
        int row0 = bm + wm + i * 16 + q * 4;
#pragma unroll
        for (int r = 0; r < 4; ++r) {
          float v = acc[i][j][r] + bs;
          if (RELU) v = fmaxf(v, 0.f);
          size_t idx = (size_t)(row0 + r) * ldc + col;
          if (OMODE == 0) {
            ((float*)Cout)[idx] = v;
          } else if (OMODE == 1) {
            ((__bf16*)Cout)[idx] = (__bf16)v;
          } else {
            ((float*)Cout)[idx] = v;
            Cout2[idx] = (__bf16)v;
          }
        }
      }
    }
  } else {
    // V region: transpose 128x128 C tile through LDS, write vT rows coalesced
    const int Vcol = bn - 2048;
    const int vl = Vcol >> 9;
    const int c512 = Vcol & 511;
    const int bb = bm / 768;
    const int w0 = bm % 768;
    __bf16* Ct = smem;  // [64][136]
    for (int hh = 0; hh < 2; ++hh) {
      __syncthreads();
      if ((wid & 1) == hh) {
#pragma unroll
        for (int j = 0; j < JN; ++j) {
          float bs = bias[bn + wn + j * 16 + mr];
#pragma unroll
          for (int i = 0; i < 4; ++i) {
            int wl = wm + i * 16 + q * 4;
            bf16x4 pk = {(__bf16)(acc[i][j][0] + bs), (__bf16)(acc[i][j][1] + bs),
                         (__bf16)(acc[i][j][2] + bs), (__bf16)(acc[i][j][3] + bs)};
            *(bf16x4*)&Ct[(j * 16 + mr) * 136 + wl] = pk;
          }
        }
      }
      __syncthreads();
      {
        int c = t >> 2, ch = t & 3;
        const __bf16* ct = &Ct[c * 136 + ch * 32];
        bf16x8 d0 = *(const bf16x8*)ct;
        bf16x8 d1 = *(const bf16x8*)(ct + 8);
        bf16x8 d2 = *(const bf16x8*)(ct + 16);
        bf16x8 d3 = *(const bf16x8*)(ct + 24);
        size_t rowV = (size_t)(vl * 16 + bb) * 512 + c512 + hh * 64 + c;
        __bf16* gp = vT + rowV * 768 + w0 + ch * 32;
        *(bf16x8*)gp = d0;
        *(bf16x8*)(gp + 8) = d1;
        *(bf16x8*)(gp + 16) = d2;
        *(bf16x8*)(gp + 24) = d3;
      }
    }
  }
}

// ---------------- MFMA flash attention (S^T variant, reg-prefetched) ----------------
// K from kvs_k [bW][2048]; V from vT [l,b][512 d-rows][768 p]. Next chunk's
// K/V prefetched into registers before compute to hide global latency.
__global__ __launch_bounds__(256) void attn_mfma_kernel(
    const __bf16* __restrict__ attbf, const __bf16* __restrict__ kvs_k,
    const __bf16* __restrict__ vT, float* __restrict__ out, int l) {
  const int b = blockIdx.z, h = blockIdx.y, qt = blockIdx.x;
  __shared__ __bf16 Ks[64 * 72];
  __shared__ __bf16 Vt[64 * 72];
  __shared__ __bf16 Ps[64 * 72];
  const int t = threadIdx.x;
  const int w = t >> 6, lane = t & 63;
  const int quad = lane >> 4, mr = lane & 15;
  bf16x8 aq[2];
  {
    const __bf16* qp = attbf + ((size_t)(b * kNV + qt * 64 + w * 16 + mr) * kHA +
                                h * kA + quad * 8);
    aq[0] = *(const bf16x8*)qp;
    aq[1] = *(const bf16x8*)(qp + 32);
  }
  f32x4 o[4] = {};
  float m_ = -1e30f, l_ = 0.f;
  const int cmax = kNH + qt * 64;
  const int pr = t >> 2, pc = t & 3;
  const __bf16* kbase = kvs_k + ((size_t)(b * kW + pr) * 2048 + l * 512 + h * kA);
  const __bf16* vbase = vT + ((size_t)((l * 16 + b) * 512) + h * kA + pr) * 768;
  bf16x8 kc0, kc1, vc0, vc1;
  kc0 = *(const bf16x8*)(kbase + pc * 8);
  kc1 = *(const bf16x8*)(kbase + pc * 8 + 32);
  vc0 = *(const bf16x8*)(vbase + pc * 16);
  vc1 = *(const bf16x8*)(vbase + pc * 16 + 8);
  for (int c0 = 0; c0 <= cmax; c0 += 64) {
    __syncthreads();  // prior chunk's LDS reads complete
    *(bf16x8*)&Ks[pr * 72 + pc * 8] = kc0;
    *(bf16x8*)&Ks[pr * 72 + pc * 8 + 32] = kc1;
    *(bf16x8*)&Vt[pr * 72 + pc * 16] = vc0;
    *(bf16x8*)&Vt[pr * 72 + pc * 16 + 8] = vc1;
    __syncthreads();
    if (c0 + 64 <= cmax) {  // prefetch next chunk (hidden behind compute)
      const __bf16* kp = kbase + (size_t)(c0 + 64) * 2048;
      const __bf16* vp = vbase + c0 + 64;
      kc0 = *(const bf16x8*)(kp + pc * 8);
      kc1 = *(const bf16x8*)(kp + pc * 8 + 32);
      vc0 = *(const bf16x8*)(vp + pc * 16);
      vc1 = *(const bf16x8*)(vp + pc * 16 + 8);
    }
    // ---- S^T = K·Q^T : s[j][r] = S[p = j*16+quad*4+r][q = mr] ----
    f32x4 s[4];
#pragma unroll
    for (int j = 0; j < 4; ++j) {
      bf16x8 ak0 = *(const bf16x8*)&Ks[(j * 16 + mr) * 72 + quad * 8];
      bf16x8 ak1 = *(const bf16x8*)&Ks[(j * 16 + mr) * 72 + quad * 8 + 32];
      f32x4 z = {};
      z = __builtin_amdgcn_mfma_f32_16x16x32_bf16(ak0, aq[0], z, 0, 0, 0);
      z = __builtin_amdgcn_mfma_f32_16x16x32_bf16(ak1, aq[1], z, 0, 0, 0);
      s[j] = z;
    }
    // ---- mask + scale + online softmax (per-lane scalar state, q = mr) ----
    const int lim = cmax - c0;
    float sv[16], mx = -1e30f;
#pragma unroll
    for (int j = 0; j < 4; ++j)
#pragma unroll
      for (int r = 0; r < 4; ++r) {
        int p = j * 16 + quad * 4 + r;
        float x = (p < lim + mr) ? s[j][r] * 0.125f : -1e30f;
        sv[j * 4 + r] = x;
        mx = fmaxf(mx, x);
      }
    mx = fmaxf(mx, __shfl_xor(mx, 16));
    mx = fmaxf(mx, __shfl_xor(mx, 32));
    float mnew = fmaxf(m_, mx);
    float corr = __expf(m_ - mnew);
    float rs = 0.f;
#pragma unroll
    for (int i = 0; i < 16; ++i) {
      sv[i] = __expf(sv[i] - mnew);
      rs += sv[i];
    }
    rs += __shfl_xor(rs, 16);
    rs += __shfl_xor(rs, 32);
    l_ = l_ * corr + rs;
    m_ = mnew;
#pragma unroll
    for (int j = 0; j < 4; ++j) {
      bf16x4 pk = {(__bf16)sv[j * 4 + 0], (__bf16)sv[j * 4 + 1],
                   (__bf16)sv[j * 4 + 2], (__bf16)sv[j * 4 + 3]};
      *(bf16x4*)&Ps[(w * 16 + mr) * 72 + j * 16 + quad * 4] = pk;
    }
#pragma unroll
    for (int r = 0; r < 4; ++r) {
      float cr = __shfl(corr, quad * 4 + r);
#pragma unroll
      for (int j = 0; j < 4; ++j) o[j][r] *= cr;
    }
    // ---- O += P·V (wave-local P read) ----
    bf16x8 ap0 = *(const bf16x8*)&Ps[(w * 16 + mr) * 72 + quad * 8];
    bf16x8 ap1 = *(const bf16x8*)&Ps[(w * 16 + mr) * 72 + quad * 8 + 32];
#pragma unroll
    for (int j = 0; j < 4; ++j) {
      bf16x8 b0 = *(const bf16x8*)&Vt[(j * 16 + mr) * 72 + quad * 8];
      bf16x8 b1 = *(const bf16x8*)&Vt[(j * 16 + mr) * 72 + quad * 8 + 32];
      o[j] = __builtin_amdgcn_mfma_f32_16x16x32_bf16(ap0, b0, o[j], 0, 0, 0);
      o[j] = __builtin_amdgcn_mfma_f32_16x16x32_bf16(ap1, b1, o[j], 0, 0, 0);
    }
  }
  float invl = 1.f / l_;
#pragma unroll
  for (int r = 0; r < 4; ++r) {
    float ir = __shfl(invl, quad * 4 + r);
    int row = b * kNV + qt * 64 + w * 16 + quad * 4 + r;
#pragma unroll
    for (int j = 0; j < 4; ++j)
      out[(size_t)row * kHA + h * kA + j * 16 + mr] = o[j][r] * ir;
  }
}

// ---------------- att = LN(att + add); float4; emits bf16 copy ----------------
__global__ __launch_bounds__(128) void add_ln_kernel(
    float* __restrict__ att, const float* __restrict__ add,
    const float* __restrict__ g, const float* __restrict__ be,
    __bf16* __restrict__ attbf) {
  const int row = blockIdx.x;
  const int t = threadIdx.x;
  float4* ar = (float4*)(att + (size_t)row * kHA);
  const float4* dr = (const float4*)(add + (size_t)row * kHA);
  float4 x = ar[t];
  float4 d = dr[t];
  x.x += d.x; x.y += d.y; x.z += d.z; x.w += d.w;
  float s = x.x + x.y + x.z + x.w;
  float sq = x.x * x.x + x.y * x.y + x.z * x.z + x.w * x.w;
  for (int o = 32; o; o >>= 1) {
    s += __shfl_xor(s, o);
    sq += __shfl_xor(sq, o);
  }
  __shared__ float red[4];
  if ((t & 63) == 0) { red[(t >> 6) * 2] = s; red[(t >> 6) * 2 + 1] = sq; }
  __syncthreads();
  float S = red[0] + red[2], Q = red[1] + red[3];
  float mean = S * (1.f / kHA);
  float inv = rsqrtf(Q * (1.f / kHA) - mean * mean + 1e-5f);
  float4 gv = ((const float4*)g)[t];
  float4 bv = ((const float4*)be)[t];
  float4 y;
  y.x = gv.x * (x.x - mean) * inv + bv.x;
  y.y = gv.y * (x.y - mean) * inv + bv.y;
  y.z = gv.z * (x.z - mean) * inv + bv.z;
  y.w = gv.w * (x.w - mean) * inv + bv.w;
  ar[t] = y;
  bf16x4 yb = {(__bf16)y.x, (__bf16)y.y, (__bf16)y.z, (__bf16)y.w};
  *(bf16x4*)(attbf + (size_t)row * kHA + t * 4) = yb;
}

// ---------------- fused de-projection + loss partials ----------------
__global__ __launch_bounds__(256) void de_loss_kernel(
    const __bf16* __restrict__ attbf, const __bf16* __restrict__ de_wt,
    const float* __restrict__ de_b, const float* __restrict__ pred_u,
    float* __restrict__ parts) {
  const int blk = blockIdx.x;
  const int t = threadIdx.x;
  const int w = t >> 6, lane = t & 63, quad = lane >> 4, mr = lane & 15;
  const int row0 = blk * 64 + w * 16;
  f32x4 acc[8] = {};
  const __bf16* Ap = attbf + (size_t)(row0 + mr) * kHA + quad * 8;
#pragma unroll 4
  for (int k0 = 0; k0 < 512; k0 += 32) {
    bf16x8 a = *(const bf16x8*)(Ap + k0);
#pragma unroll
    for (int j = 0; j < 8; ++j) {
      bf16x8 bb =
          *(const bf16x8*)(de_wt + (size_t)(j * 16 + mr) * 512 + k0 + quad * 8);
      acc[j] = __builtin_amdgcn_mfma_f32_16x16x32_bf16(a, bb, acc[j], 0, 0, 0);
    }
  }
  float dbv[8];
#pragma unroll
  for (int j = 0; j < 8; ++j) dbv[j] = de_b[j * 16 + mr];
  float lpacc = 0.f;
#pragma unroll
  for (int r = 0; r < 4; ++r) {
    int row = row0 + quad * 4 + r;
    int v = row & 255, bidx = row >> 8;
    float lg[8], mx = -1e30f;
#pragma unroll
    for (int j = 0; j < 8; ++j) {
      lg[j] = acc[j][r] + dbv[j];
      mx = fmaxf(mx, lg[j]);
    }
    mx = fmaxf(mx, __shfl_xor(mx, 1));
    mx = fmaxf(mx, __shfl_xor(mx, 2));
    mx = fmaxf(mx, __shfl_xor(mx, 4));
    mx = fmaxf(mx, __shfl_xor(mx, 8));
    float se = 0.f;
#pragma unroll
    for (int j = 0; j < 8; ++j) se += __expf(lg[j] - mx);
    se += __shfl_xor(se, 1);
    se += __shfl_xor(se, 2);
    se += __shfl_xor(se, 4);
    se += __shfl_xor(se, 8);
    float lse = mx + __logf(se);
    float u = pred_u[bidx * 256 + v];
    int tgt = (int)floorf(u * 128.f);
    tgt = max(0, min(127, tgt));
    float cand = (mr == (tgt & 15)) ? lg[tgt >> 4] : 0.f;
    cand += __shfl_xor(cand, 1);
    cand += __shfl_xor(cand, 2);
    cand += __shfl_xor(cand, 4);
    cand += __shfl_xor(cand, 8);
    float lp = (v >= 1) ? (4.8520302639196171f + cand - lse) : 0.f;  // ln(128)
    lpacc += lp;
  }
  lpacc += __shfl_xor(lpacc, 16);
  lpacc += __shfl_xor(lpacc, 32);
  __shared__ float red[4];
  if (lane == 0) red[w] = lpacc;
  __syncthreads();
  if (t == 0) parts[blk] = red[0] + red[1] + red[2] + red[3];
}

__global__ void loss_final_kernel(const float* __restrict__ parts,
                                  float* __restrict__ out) {
  int b = threadIdx.x;
  if (b < kB)
    out[b] = -(parts[b * 4] + parts[b * 4 + 1] + parts[b * 4 + 2] +
               parts[b * 4 + 3]);
}

extern "C" void kernel_launch(void* const* d_in, const int* in_sizes, int n_in,
                              void* d_out, int out_size, void* d_ws, size_t ws_size,
                              hipStream_t stream) {
  const float* hist   = (const float*)d_in[0];
  const float* hist_u = (const float*)d_in[1];
  const float* pred   = (const float*)d_in[2];
  const float* pred_u = (const float*)d_in[3];
  const float* ds_w   = (const float*)d_in[4];
  const float* ds_b   = (const float*)d_in[5];
  const float* key_w  = (const float*)d_in[6];
  const float* key_b  = (const float*)d_in[7];
  const float* val_w  = (const float*)d_in[8];
  const float* val_b  = (const float*)d_in[9];
  const float* ln1_g  = (const float*)d_in[10];
  const float* ln1_b  = (const float*)d_in[11];
  const float* ln2_g  = (const float*)d_in[12];
  const float* ln2_b  = (const float*)d_in[13];
  const float* ff_w1  = (const float*)d_in[14];
  const float* ff_b1  = (const float*)d_in[15];
  const float* ff_w2  = (const float*)d_in[16];
  const float* ff_b2  = (const float*)d_in[17];
  const float* ff_w3  = (const float*)d_in[18];
  const float* ff_b3  = (const float*)d_in[19];
  const float* de_w   = (const float*)d_in[20];
  const float* de_b   = (const float*)d_in[21];
  float* out = (float*)d_out;

  char* ws = (char*)d_ws;
  size_t off = 0;
  auto alloc = [&](size_t bytes) { char* p = ws + off; off += bytes; return p; };
  __bf16* ki_bf  = (__bf16*)alloc((size_t)kB * kW * kKP * 2);       // 7.1 MB
  __bf16* kv_wt  = (__bf16*)alloc((size_t)4096 * kKP * 2);          // 2.4 MB
  __bf16* ffw_t  = (__bf16*)alloc((size_t)12 * 512 * 512 * 2);      // 6.3 MB
  __bf16* ds_wt  = (__bf16*)alloc((size_t)512 * 256 * 2);
  __bf16* de_wt  = (__bf16*)alloc((size_t)128 * 512 * 2);
  float*  kvb    = (float*)alloc((size_t)4096 * 4);
  __bf16* kvs_k  = (__bf16*)alloc((size_t)kB * kW * 2048 * 2);      // 50.3 MB
  __bf16* vT     = (__bf16*)alloc((size_t)kL * kB * 512 * 768 * 2); // 50.3 MB
  float*  att    = (float*)alloc((size_t)kB * kNV * kHA * 4);       // 8.4 MB
  __bf16* att_bf = (__bf16*)alloc((size_t)kB * kNV * kHA * 2);
  float*  tmp    = (float*)alloc((size_t)kB * kNV * kHA * 4);
  __bf16* ff1_bf = (__bf16*)alloc((size_t)kB * kNV * kM * 2);
  __bf16* ff2_bf = (__bf16*)alloc((size_t)kB * kNV * kM * 2);
  float*  parts  = (float*)alloc(64 * 4);

  build_ki_bf_kernel<<<(kB * kW * kKP + 255) / 256, 256, 0, stream>>>(
      hist, hist_u, pred, pred_u, ki_bf);
  conv_kvw_kernel<<<(4096 * kKP + 255) / 256, 256, 0, stream>>>(key_w, val_w,
                                                                kv_wt);
  conv_ffw_kernel<<<(12 * 512 * 512 + 255) / 256, 256, 0, stream>>>(ff_w1, ff_w2,
                                                                    ff_w3, ffw_t);
  conv_misc_kernel<<<(200704 + 255) / 256, 256, 0, stream>>>(
      ds_w, de_w, key_b, val_b, ds_wt, de_wt, kvb);

  // att = pred @ ds_w + ds_b (fp32 + bf16); A = pred rows inside ki (KIMAP)
  gemm_mfma_kernel<64, 2, false, true, false>
      <<<dim3(kHA / 64, kB * kNV / 128), 256, 0, stream>>>(
          ki_bf, ds_wt, ds_b, att, att_bf, nullptr, kB * kNV, kHA, kD, kKP, kHA);

  // keys (cols<2048 -> kvs_k) and values (cols>=2048 -> vT, transposed)
  gemm_mfma_kernel<128, 1, false, false, true>
      <<<dim3(4096 / 128, kB * kW / 128), 256, 0, stream>>>(
          ki_bf, kv_wt, kvb, kvs_k, nullptr, vT, kB * kW, 4096, kKP, kKP, 2048);

  for (int l = 0; l < kL; ++l) {
    attn_mfma_kernel<<<dim3(kNV / 64, kH, kB), 256, 0, stream>>>(
        att_bf, kvs_k, vT, tmp, l);
    add_ln_kernel<<<kB * kNV, 128, 0, stream>>>(att, tmp, ln1_g + l * kHA,
                                                ln1_b + l * kHA, att_bf);
    gemm_mfma_kernel<64, 1, true, false, false>
        <<<dim3(kM / 64, kB * kNV / 128), 256, 0, stream>>>(
            att_bf, ffw_t + (size_t)(l * 3) * 262144, ff_b1 + l * kM, ff1_bf,
            nullptr, nullptr, kB * kNV, kM, kHA, kHA, kM);
    gemm_mfma_kernel<64, 1, true, false, false>
        <<<dim3(kM / 64, kB * kNV / 128), 256, 0, stream>>>(
            ff1_bf, ffw_t + (size_t)(l * 3 + 1) * 262144, ff_b2 + l * kM, ff2_bf,
            nullptr, nullptr, kB * kNV, kM, kM, kM, kM);
    gemm_mfma_kernel<64, 0, false, false, false>
        <<<dim3(kHA / 64, kB * kNV / 128), 256, 0, stream>>>(
            ff2_bf, ffw_t + (size_t)(l * 3 + 2) * 262144, ff_b3 + l * kHA, tmp,
            nullptr, nullptr, kB * kNV, kHA, kM, kM, kHA);
    add_ln_kernel<<<kB * kNV, 128, 0, stream>>>(att, tmp, ln2_g + l * kHA,
                                                ln2_b + l * kHA, att_bf);
  }
  de_loss_kernel<<<64, 256, 0, stream>>>(att_bf, de_wt, de_b, pred_u, parts);
  loss_final_kernel<<<1, 64, 0, stream>>>(parts, out);
}

// Round 7
// 492.330 us; speedup vs baseline: 9.6307x; 1.0569x over previous
//
#include <hip/hip_runtime.h>

// Problem constants (AttentionalCopula)
constexpr int kB = 16, kD = 256, kNH = 512, kNV = 256, kW = 768;
constexpr int kL = 4, kH = 8, kA = 64, kHA = 512, kM = 512, kR = 128;
constexpr int kKP = 288;  // K=257 zero-padded to multiple of 32

typedef __bf16 bf16x8 __attribute__((ext_vector_type(8)));
typedef __bf16 bf16x4 __attribute__((ext_vector_type(4)));
typedef float f32x4 __attribute__((ext_vector_type(4)));

__device__ inline void load_lds16(const __bf16* g, __bf16* l) {
  __builtin_amdgcn_global_load_lds(
      (const __attribute__((address_space(1))) void*)g,
      (__attribute__((address_space(3))) void*)l, 16, 0, 0);
}

// ---------------- merged prep kernel (1 launch) ----------------
// ranges: [0,N1) build_ki; [N1,N1+N2) conv_kvw; then conv_ffw; then misc.
constexpr int kP1 = kB * kW * kKP;        // 3,538,944
constexpr int kP2 = 4096 * kKP;           // 1,179,648
constexpr int kP3 = 12 * 512 * 512;       // 3,145,728
constexpr int kP4 = 200704;
constexpr int kPT = kP1 + kP2 + kP3 + kP4;

__global__ void prep_kernel(const float* __restrict__ hist,
                            const float* __restrict__ hist_u,
                            const float* __restrict__ pred,
                            const float* __restrict__ pred_u,
                            const float* __restrict__ kw,
                            const float* __restrict__ vw,
                            const float* __restrict__ w1,
                            const float* __restrict__ w2,
                            const float* __restrict__ w3,
                            const float* __restrict__ ds_w,
                            const float* __restrict__ de_w,
                            const float* __restrict__ key_b,
                            const float* __restrict__ val_b,
                            __bf16* __restrict__ ki,
                            __bf16* __restrict__ kvwt,
                            __bf16* __restrict__ ffwt,
                            __bf16* __restrict__ ds_wt,
                            __bf16* __restrict__ de_wt,
                            float* __restrict__ kvb) {
  int i = blockIdx.x * 256 + threadIdx.x;
  if (i < kP1) {
    int d = i % kKP;
    int bw = i / kKP;
    int w = bw % kW;
    int b = bw / kW;
    float v = 0.f;
    if (d < 257) {
      if (w < kNH)
        v = (d < kD) ? hist[((size_t)b * kNH + w) * kD + d] : hist_u[b * kNH + w];
      else {
        int p = w - kNH;
        v = (d < kD) ? pred[((size_t)b * kNV + p) * kD + d] : pred_u[b * kNV + p];
      }
    }
    ki[i] = (__bf16)v;
  } else if (i < kP1 + kP2) {
    int j = i - kP1;
    int d = j % kKP;
    int c = j / kKP;
    float v = 0.f;
    if (d < 257) {
      bool isv = c >= 2048;
      int cc = isv ? c - 2048 : c;
      int l = cc >> 9, rest = cc & 511;
      int h = rest >> 6, a = rest & 63;
      size_t src = (((size_t)l * kH + h) * 257 + d) * kA + a;
      v = isv ? vw[src] : kw[src];
    }
    kvwt[j] = (__bf16)v;
  } else if (i < kP1 + kP2 + kP3) {
    int j = i - kP1 - kP2;
    int k = j & 511;
    int n = (j >> 9) & 511;
    int mat = j >> 18;
    int l = mat / 3, which = mat % 3;
    const float* src = which == 0 ? w1 : which == 1 ? w2 : w3;
    ffwt[j] = (__bf16)src[((size_t)l * 512 + k) * 512 + n];
  } else if (i < kPT) {
    int j = i - kP1 - kP2 - kP3;
    if (j < 131072) {
      int n = j >> 8, k = j & 255;
      ds_wt[j] = (__bf16)ds_w[k * 512 + n];
    } else if (j < 196608) {
      int jj = j - 131072;
      int n = jj >> 9, k = jj & 511;
      de_wt[jj] = (__bf16)de_w[k * 128 + n];
    } else {
      int c = j - 196608;  // 0..4095
      bool isv = c >= 2048;
      int cc = isv ? c - 2048 : c;
      int l = cc >> 9, rest = cc & 511;
      kvb[c] = isv ? val_b[l * 512 + rest] : key_b[l * 512 + rest];
    }
  }
}

// ---------------- bf16 MFMA GEMM ----------------
// C[M,N] = A[M,K]@B[K,N] + bias; Bt = B transposed [N][K]. BM=128, BN 64/128.
// XOR-swizzled LDS (chunk ^= (row>>1)&3). KIMAP: A rows remap
// r -> (r>>8)*768 + 512 + (r&255). BIASROW: bias indexed by row (for the
// operand-swapped V^T GEMM).
template <int BN, int OMODE, bool RELU, bool KIMAP, bool BIASROW>
__global__ __launch_bounds__(256) void gemm_mfma_kernel(
    const __bf16* __restrict__ A, const __bf16* __restrict__ Bt,
    const float* __restrict__ bias, void* __restrict__ Cout,
    __bf16* __restrict__ Cout2, int M, int N, int K, int lda, int ldc) {
  constexpr int JN = BN / 32;
  constexpr int BROWS = BN / 4;
  __shared__ __bf16 As[128 * 32];
  __shared__ __bf16 Bs[BN * 32];
  const int t = threadIdx.x;
  const int wid = t >> 6;
  const int lane = t & 63;
  const int bm = blockIdx.y * 128;
  const int bn = blockIdx.x * BN;
  const int wm = (wid >> 1) * 64;
  const int wn = (wid & 1) * (BN / 2);
  const int sr = lane >> 2, sc = lane & 3;
  const int skey = (sr >> 1) & 3;
  const int abase = KIMAP ? ((bm >> 8) * 768 + 512 + (bm & 255)) : bm;
  const __bf16* Ag = A + (size_t)(abase + wid * 32 + sr) * lda + (sc ^ skey) * 8;
  const __bf16* Bg = Bt + (size_t)(bn + wid * BROWS + sr) * K + (sc ^ skey) * 8;
  __bf16* AsW = As + (wid * 32) * 32;
  __bf16* BsW = Bs + (wid * BROWS) * 32;

  f32x4 acc[4][JN] = {};
  const int q = lane >> 4, mr = lane & 15;
  const int rkey = (mr >> 1) & 3;
  for (int k0 = 0; k0 < K; k0 += 32) {
    if (k0) __syncthreads();
    load_lds16(Ag + k0, AsW);
    load_lds16(Ag + (size_t)16 * lda + k0, AsW + 16 * 32);
    load_lds16(Bg + k0, BsW);
    if (BN == 128) load_lds16(Bg + (size_t)16 * K + k0, BsW + 16 * 32);
    __syncthreads();
    bf16x8 af[4], bfr[JN];
#pragma unroll
    for (int i = 0; i < 4; ++i)
      af[i] = *(const bf16x8*)(As + (wm + i * 16 + mr) * 32 + (q ^ rkey) * 8);
#pragma unroll
    for (int j = 0; j < JN; ++j)
      bfr[j] = *(const bf16x8*)(Bs + (wn + j * 16 + mr) * 32 + (q ^ rkey) * 8);
#pragma unroll
    for (int i = 0; i < 4; ++i)
#pragma unroll
      for (int j = 0; j < JN; ++j)
        acc[i][j] = __builtin_amdgcn_mfma_f32_16x16x32_bf16(af[i], bfr[j],
                                                            acc[i][j], 0, 0, 0);
  }
#pragma unroll
  for (int j = 0; j < JN; ++j) {
    int col = bn + wn + j * 16 + mr;
    float bscol = BIASROW ? 0.f : bias[col];
#pragma unroll
    for (int i = 0; i < 4; ++i) {
      int row0 = bm + wm + i * 16 + q * 4;
#pragma unroll
      for (int r = 0; r < 4; ++r) {
        float v = acc[i][j][r] + (BIASROW ? bias[row0 + r] : bscol);
        if (RELU) v = fmaxf(v, 0.f);
        size_t idx = (size_t)(row0 + r) * ldc + col;
        if (OMODE == 0) {
          ((float*)Cout)[idx] = v;
        } else if (OMODE == 1) {
          ((__bf16*)Cout)[idx] = (__bf16)v;
        } else {
          ((float*)Cout)[idx] = v;
          Cout2[idx] = (__bf16)v;
        }
      }
    }
  }
}

// ---------------- MFMA flash attention (S^T variant, reg-prefetched) ----------------
// K from kvs_k [bW][2048]; V from vT [2048 d-rows][12288 w-cols]. Next chunk
// prefetched into registers before compute.
__global__ __launch_bounds__(256) void attn_mfma_kernel(
    const __bf16* __restrict__ attbf, const __bf16* __restrict__ kvs_k,
    const __bf16* __restrict__ vT, __bf16* __restrict__ outbf, int l) {
  const int b = blockIdx.z, h = blockIdx.y, qt = blockIdx.x;
  __shared__ __bf16 Ks[64 * 72];
  __shared__ __bf16 Vt[64 * 72];
  __shared__ __bf16 Ps[64 * 72];
  const int t = threadIdx.x;
  const int w = t >> 6, lane = t & 63;
  const int quad = lane >> 4, mr = lane & 15;
  bf16x8 aq[2];
  {
    const __bf16* qp = attbf + ((size_t)(b * kNV + qt * 64 + w * 16 + mr) * kHA +
                                h * kA + quad * 8);
    aq[0] = *(const bf16x8*)qp;
    aq[1] = *(const bf16x8*)(qp + 32);
  }
  f32x4 o[4] = {};
  float m_ = -1e30f, l_ = 0.f;
  const int cmax = kNH + qt * 64;
  const int pr = t >> 2, pc = t & 3;
  const __bf16* kbase = kvs_k + ((size_t)(b * kW + pr) * 2048 + l * 512 + h * kA);
  const __bf16* vbase = vT + (size_t)(l * 512 + h * kA + pr) * 12288 + b * kW;
  bf16x8 kc0, kc1, vc0, vc1;
  kc0 = *(const bf16x8*)(kbase + pc * 8);
  kc1 = *(const bf16x8*)(kbase + pc * 8 + 32);
  vc0 = *(const bf16x8*)(vbase + pc * 16);
  vc1 = *(const bf16x8*)(vbase + pc * 16 + 8);
  for (int c0 = 0; c0 <= cmax; c0 += 64) {
    __syncthreads();  // prior chunk's LDS reads complete
    *(bf16x8*)&Ks[pr * 72 + pc * 8] = kc0;
    *(bf16x8*)&Ks[pr * 72 + pc * 8 + 32] = kc1;
    *(bf16x8*)&Vt[pr * 72 + pc * 16] = vc0;
    *(bf16x8*)&Vt[pr * 72 + pc * 16 + 8] = vc1;
    __syncthreads();
    if (c0 + 64 <= cmax) {  // prefetch next chunk (hidden behind compute)
      const __bf16* kp = kbase + (size_t)(c0 + 64) * 2048;
      const __bf16* vp = vbase + c0 + 64;
      kc0 = *(const bf16x8*)(kp + pc * 8);
      kc1 = *(const bf16x8*)(kp + pc * 8 + 32);
      vc0 = *(const bf16x8*)(vp + pc * 16);
      vc1 = *(const bf16x8*)(vp + pc * 16 + 8);
    }
    // ---- S^T = K·Q^T : s[j][r] = S[p = j*16+quad*4+r][q = mr] ----
    f32x4 s[4];
#pragma unroll
    for (int j = 0; j < 4; ++j) {
      bf16x8 ak0 = *(const bf16x8*)&Ks[(j * 16 + mr) * 72 + quad * 8];
      bf16x8 ak1 = *(const bf16x8*)&Ks[(j * 16 + mr) * 72 + quad * 8 + 32];
      f32x4 z = {};
      z = __builtin_amdgcn_mfma_f32_16x16x32_bf16(ak0, aq[0], z, 0, 0, 0);
      z = __builtin_amdgcn_mfma_f32_16x16x32_bf16(ak1, aq[1], z, 0, 0, 0);
      s[j] = z;
    }
    // ---- mask + scale + online softmax (per-lane scalar state, q = mr) ----
    const int lim = cmax - c0;
    float sv[16], mx = -1e30f;
#pragma unroll
    for (int j = 0; j < 4; ++j)
#pragma unroll
      for (int r = 0; r < 4; ++r) {
        int p = j * 16 + quad * 4 + r;
        float x = (p < lim + mr) ? s[j][r] * 0.125f : -1e30f;
        sv[j * 4 + r] = x;
        mx = fmaxf(mx, x);
      }
    mx = fmaxf(mx, __shfl_xor(mx, 16));
    mx = fmaxf(mx, __shfl_xor(mx, 32));
    float mnew = fmaxf(m_, mx);
    float corr = __expf(m_ - mnew);
    float rs = 0.f;
#pragma unroll
    for (int i = 0; i < 16; ++i) {
      sv[i] = __expf(sv[i] - mnew);
      rs += sv[i];
    }
    rs += __shfl_xor(rs, 16);
    rs += __shfl_xor(rs, 32);
    l_ = l_ * corr + rs;
    m_ = mnew;
#pragma unroll
    for (int j = 0; j < 4; ++j) {
      bf16x4 pk = {(__bf16)sv[j * 4 + 0], (__bf16)sv[j * 4 + 1],
                   (__bf16)sv[j * 4 + 2], (__bf16)sv[j * 4 + 3]};
      *(bf16x4*)&Ps[(w * 16 + mr) * 72 + j * 16 + quad * 4] = pk;
    }
#pragma unroll
    for (int r = 0; r < 4; ++r) {
      float cr = __shfl(corr, quad * 4 + r);
#pragma unroll
      for (int j = 0; j < 4; ++j) o[j][r] *= cr;
    }
    // ---- O += P·V (wave-local P read) ----
    bf16x8 ap0 = *(const bf16x8*)&Ps[(w * 16 + mr) * 72 + quad * 8];
    bf16x8 ap1 = *(const bf16x8*)&Ps[(w * 16 + mr) * 72 + quad * 8 + 32];
#pragma unroll
    for (int j = 0; j < 4; ++j) {
      bf16x8 b0 = *(const bf16x8*)&Vt[(j * 16 + mr) * 72 + quad * 8];
      bf16x8 b1 = *(const bf16x8*)&Vt[(j * 16 + mr) * 72 + quad * 8 + 32];
      o[j] = __builtin_amdgcn_mfma_f32_16x16x32_bf16(ap0, b0, o[j], 0, 0, 0);
      o[j] = __builtin_amdgcn_mfma_f32_16x16x32_bf16(ap1, b1, o[j], 0, 0, 0);
    }
  }
  float invl = 1.f / l_;
#pragma unroll
  for (int r = 0; r < 4; ++r) {
    float ir = __shfl(invl, quad * 4 + r);
    int row = b * kNV + qt * 64 + w * 16 + quad * 4 + r;
#pragma unroll
    for (int j = 0; j < 4; ++j)
      outbf[(size_t)row * kHA + h * kA + j * 16 + mr] = (__bf16)(o[j][r] * ir);
  }
}

// ---------------- att = LN(att + add_bf); emits bf16 copy ----------------
__global__ __launch_bounds__(128) void add_ln_kernel(
    float* __restrict__ att, const __bf16* __restrict__ addbf,
    const float* __restrict__ g, const float* __restrict__ be,
    __bf16* __restrict__ attbf) {
  const int row = blockIdx.x;
  const int t = threadIdx.x;
  float4* ar = (float4*)(att + (size_t)row * kHA);
  bf16x4 dv = *(const bf16x4*)(addbf + (size_t)row * kHA + t * 4);
  float4 x = ar[t];
  x.x += (float)dv[0]; x.y += (float)dv[1];
  x.z += (float)dv[2]; x.w += (float)dv[3];
  float s = x.x + x.y + x.z + x.w;
  float sq = x.x * x.x + x.y * x.y + x.z * x.z + x.w * x.w;
  for (int o = 32; o; o >>= 1) {
    s += __shfl_xor(s, o);
    sq += __shfl_xor(sq, o);
  }
  __shared__ float red[4];
  if ((t & 63) == 0) { red[(t >> 6) * 2] = s; red[(t >> 6) * 2 + 1] = sq; }
  __syncthreads();
  float S = red[0] + red[2], Q = red[1] + red[3];
  float mean = S * (1.f / kHA);
  float inv = rsqrtf(Q * (1.f / kHA) - mean * mean + 1e-5f);
  float4 gv = ((const float4*)g)[t];
  float4 bv = ((const float4*)be)[t];
  float4 y;
  y.x = gv.x * (x.x - mean) * inv + bv.x;
  y.y = gv.y * (x.y - mean) * inv + bv.y;
  y.z = gv.z * (x.z - mean) * inv + bv.z;
  y.w = gv.w * (x.w - mean) * inv + bv.w;
  ar[t] = y;
  bf16x4 yb = {(__bf16)y.x, (__bf16)y.y, (__bf16)y.z, (__bf16)y.w};
  *(bf16x4*)(attbf + (size_t)row * kHA + t * 4) = yb;
}

// ---------------- fused de-projection + loss partials ----------------
__global__ __launch_bounds__(256) void de_loss_kernel(
    const __bf16* __restrict__ attbf, const __bf16* __restrict__ de_wt,
    const float* __restrict__ de_b, const float* __restrict__ pred_u,
    float* __restrict__ parts) {
  const int blk = blockIdx.x;
  const int t = threadIdx.x;
  const int w = t >> 6, lane = t & 63, quad = lane >> 4, mr = lane & 15;
  const int row0 = blk * 64 + w * 16;
  f32x4 acc[8] = {};
  const __bf16* Ap = attbf + (size_t)(row0 + mr) * kHA + quad * 8;
#pragma unroll 4
  for (int k0 = 0; k0 < 512; k0 += 32) {
    bf16x8 a = *(const bf16x8*)(Ap + k0);
#pragma unroll
    for (int j = 0; j < 8; ++j) {
      bf16x8 bb =
          *(const bf16x8*)(de_wt + (size_t)(j * 16 + mr) * 512 + k0 + quad * 8);
      acc[j] = __builtin_amdgcn_mfma_f32_16x16x32_bf16(a, bb, acc[j], 0, 0, 0);
    }
  }
  float dbv[8];
#pragma unroll
  for (int j = 0; j < 8; ++j) dbv[j] = de_b[j * 16 + mr];
  float lpacc = 0.f;
#pragma unroll
  for (int r = 0; r < 4; ++r) {
    int row = row0 + quad * 4 + r;
    int v = row & 255, bidx = row >> 8;
    float lg[8], mx = -1e30f;
#pragma unroll
    for (int j = 0; j < 8; ++j) {
      lg[j] = acc[j][r] + dbv[j];
      mx = fmaxf(mx, lg[j]);
    }
    mx = fmaxf(mx, __shfl_xor(mx, 1));
    mx = fmaxf(mx, __shfl_xor(mx, 2));
    mx = fmaxf(mx, __shfl_xor(mx, 4));
    mx = fmaxf(mx, __shfl_xor(mx, 8));
    float se = 0.f;
#pragma unroll
    for (int j = 0; j < 8; ++j) se += __expf(lg[j] - mx);
    se += __shfl_xor(se, 1);
    se += __shfl_xor(se, 2);
    se += __shfl_xor(se, 4);
    se += __shfl_xor(se, 8);
    float lse = mx + __logf(se);
    float u = pred_u[bidx * 256 + v];
    int tgt = (int)floorf(u * 128.f);
    tgt = max(0, min(127, tgt));
    float cand = (mr == (tgt & 15)) ? lg[tgt >> 4] : 0.f;
    cand += __shfl_xor(cand, 1);
    cand += __shfl_xor(cand, 2);
    cand += __shfl_xor(cand, 4);
    cand += __shfl_xor(cand, 8);
    float lp = (v >= 1) ? (4.8520302639196171f + cand - lse) : 0.f;  // ln(128)
    lpacc += lp;
  }
  lpacc += __shfl_xor(lpacc, 16);
  lpacc += __shfl_xor(lpacc, 32);
  __shared__ float red[4];
  if (lane == 0) red[w] = lpacc;
  __syncthreads();
  if (t == 0) parts[blk] = red[0] + red[1] + red[2] + red[3];
}

__global__ void loss_final_kernel(const float* __restrict__ parts,
                                  float* __restrict__ out) {
  int b = threadIdx.x;
  if (b < kB)
    out[b] = -(parts[b * 4] + parts[b * 4 + 1] + parts[b * 4 + 2] +
               parts[b * 4 + 3]);
}

extern "C" void kernel_launch(void* const* d_in, const int* in_sizes, int n_in,
                              void* d_out, int out_size, void* d_ws, size_t ws_size,
                              hipStream_t stream) {
  const float* hist   = (const float*)d_in[0];
  const float* hist_u = (const float*)d_in[1];
  const float* pred   = (const float*)d_in[2];
  const float* pred_u = (const float*)d_in[3];
  const float* ds_w   = (const float*)d_in[4];
  const float* ds_b   = (const float*)d_in[5];
  const float* key_w  = (const float*)d_in[6];
  const float* key_b  = (const float*)d_in[7];
  const float* val_w  = (const float*)d_in[8];
  const float* val_b  = (const float*)d_in[9];
  const float* ln1_g  = (const float*)d_in[10];
  const float* ln1_b  = (const float*)d_in[11];
  const float* ln2_g  = (const float*)d_in[12];
  const float* ln2_b  = (const float*)d_in[13];
  const float* ff_w1  = (const float*)d_in[14];
  const float* ff_b1  = (const float*)d_in[15];
  const float* ff_w2  = (const float*)d_in[16];
  const float* ff_b2  = (const float*)d_in[17];
  const float* ff_w3  = (const float*)d_in[18];
  const float* ff_b3  = (const float*)d_in[19];
  const float* de_w   = (const float*)d_in[20];
  const float* de_b   = (const float*)d_in[21];
  float* out = (float*)d_out;

  char* ws = (char*)d_ws;
  size_t off = 0;
  auto alloc = [&](size_t bytes) { char* p = ws + off; off += bytes; return p; };
  __bf16* ki_bf  = (__bf16*)alloc((size_t)kB * kW * kKP * 2);       // 7.1 MB
  __bf16* kv_wt  = (__bf16*)alloc((size_t)4096 * kKP * 2);          // 2.4 MB
  __bf16* ffw_t  = (__bf16*)alloc((size_t)12 * 512 * 512 * 2);      // 6.3 MB
  __bf16* ds_wt  = (__bf16*)alloc((size_t)512 * 256 * 2);
  __bf16* de_wt  = (__bf16*)alloc((size_t)128 * 512 * 2);
  float*  kvb    = (float*)alloc((size_t)4096 * 4);
  __bf16* kvs_k  = (__bf16*)alloc((size_t)kB * kW * 2048 * 2);      // 50.3 MB
  __bf16* vT     = (__bf16*)alloc((size_t)2048 * 12288 * 2);        // 50.3 MB
  float*  att    = (float*)alloc((size_t)kB * kNV * kHA * 4);       // 8.4 MB
  __bf16* att_bf = (__bf16*)alloc((size_t)kB * kNV * kHA * 2);
  __bf16* tmp_bf = (__bf16*)alloc((size_t)kB * kNV * kHA * 2);
  __bf16* ff1_bf = (__bf16*)alloc((size_t)kB * kNV * kM * 2);
  __bf16* ff2_bf = (__bf16*)alloc((size_t)kB * kNV * kM * 2);
  float*  parts  = (float*)alloc(64 * 4);

  prep_kernel<<<(kPT + 255) / 256, 256, 0, stream>>>(
      hist, hist_u, pred, pred_u, key_w, val_w, ff_w1, ff_w2, ff_w3, ds_w, de_w,
      key_b, val_b, ki_bf, kv_wt, ffw_t, ds_wt, de_wt, kvb);

  // att = pred @ ds_w + ds_b (fp32 + bf16); A = pred rows inside ki (KIMAP)
  gemm_mfma_kernel<64, 2, false, true, false>
      <<<dim3(kHA / 64, kB * kNV / 128), 256, 0, stream>>>(
          ki_bf, ds_wt, ds_b, att, att_bf, kB * kNV, kHA, kD, kKP, kHA);

  // keys: [12288][2048] = ki @ Wk
  gemm_mfma_kernel<128, 1, false, false, false>
      <<<dim3(2048 / 128, kB * kW / 128), 256, 0, stream>>>(
          ki_bf, kv_wt, kvb, kvs_k, nullptr, kB * kW, 2048, kKP, kKP, 2048);
  // values^T: [2048][12288] = Wv^T @ ki^T (operand swap; bias per row)
  gemm_mfma_kernel<128, 1, false, false, true>
      <<<dim3(kB * kW / 128, 2048 / 128), 256, 0, stream>>>(
          kv_wt + (size_t)2048 * kKP, ki_bf, kvb + 2048, vT, nullptr, 2048,
          kB * kW, kKP, kKP, kB * kW);

  for (int l = 0; l < kL; ++l) {
    attn_mfma_kernel<<<dim3(kNV / 64, kH, kB), 256, 0, stream>>>(
        att_bf, kvs_k, vT, tmp_bf, l);
    add_ln_kernel<<<kB * kNV, 128, 0, stream>>>(att, tmp_bf, ln1_g + l * kHA,
                                                ln1_b + l * kHA, att_bf);
    gemm_mfma_kernel<64, 1, true, false, false>
        <<<dim3(kM / 64, kB * kNV / 128), 256, 0, stream>>>(
            att_bf, ffw_t + (size_t)(l * 3) * 262144, ff_b1 + l * kM, ff1_bf,
            nullptr, kB * kNV, kM, kHA, kHA, kM);
    gemm_mfma_kernel<64, 1, true, false, false>
        <<<dim3(kM / 64, kB * kNV / 128), 256, 0, stream>>>(
            ff1_bf, ffw_t + (size_t)(l * 3 + 1) * 262144, ff_b2 + l * kM, ff2_bf,
            nullptr, kB * kNV, kM, kM, kM, kM);
    gemm_mfma_kernel<64, 1, false, false, false>
        <<<dim3(kHA / 64, kB * kNV / 128), 256, 0, stream>>>(
            ff2_bf, ffw_t + (size_t)(l * 3 + 2) * 262144, ff_b3 + l * kHA, tmp_bf,
            nullptr, kB * kNV, kHA, kM, kM, kHA);
    add_ln_kernel<<<kB * kNV, 128, 0, stream>>>(att, tmp_bf, ln2_g + l * kHA,
                                                ln2_b + l * kHA, att_bf);
  }
  de_loss_kernel<<<64, 256, 0, stream>>>(att_bf, de_wt, de_b, pred_u, parts);
  loss_final_kernel<<<1, 64, 0, stream>>>(parts, out);
}